// Round 5
// baseline (319.733 us; speedup 1.0000x reference)
//
#include <hip/hip_runtime.h>
#include <hip/hip_bf16.h>
#include <math.h>

#define N_NODES 10000
#define N_EDGES 160000
#define N_GRAPHS 64
#define F_IN    128
#define C1_DIM  128
#define C2_DIM  256
#define C3_DIM  512
#define K_CHEB  5
#define NCLS    10
#define TC      (K_CHEB * F_IN)    // 640

typedef short v8s __attribute__((ext_vector_type(8)));
typedef float v4f __attribute__((ext_vector_type(4)));

// ---------- bf16 helpers ----------
static __device__ __forceinline__ unsigned short f2bf(float f) {
    unsigned u = __float_as_uint(f);
    unsigned r = (u + 0x7FFFu + ((u >> 16) & 1u)) >> 16;   // RNE
    return (unsigned short)r;
}
static __device__ __forceinline__ float bf_lo(unsigned u) { return __uint_as_float(u << 16); }
static __device__ __forceinline__ float bf_hi(unsigned u) { return __uint_as_float(u & 0xFFFF0000u); }

// ---------- fused prep ----------
// R2/R3 lesson: grid-wide fusion is DEAD on MI355X (grid.sync ~65-100us, custom
// slot barrier worse: cross-XCD fence + spin traffic). R4 lesson: pool with 64
// blocks = 1.9% occupancy = 62us. This round: pool at G*8 blocks + last-block FC;
// GCN gathers fused INTO their GEMMs (block-local rows only -> no cross-block dep).
#define PREP_A (N_NODES * 32)            // x conv, 4 floats per item
#define PREP_B (TC * C1_DIM)             // W_cheb transpose (write-coalesced)
#define PREP_C (C1_DIM * C2_DIM)         // W_g1
#define PREP_D (C2_DIM * C3_DIM)         // W_g2
#define PREP_E N_NODES                   // gptr
#define PREP_F N_NODES                   // zero logits
#define PREP_H (N_GRAPHS * C3_DIM)       // zero pooled
#define PREP_G N_EDGES                   // degree count (guarded tail)
#define PREP_TOTAL (PREP_A + PREP_B + PREP_C + PREP_D + PREP_E + PREP_F + PREP_H + PREP_G)
__global__ void prep_kernel(const float* __restrict__ x, unsigned short* __restrict__ tcat,
                            const float* __restrict__ Wcheb, unsigned short* __restrict__ Wcb_t,
                            const float* __restrict__ Wg1, unsigned short* __restrict__ Wg1_t,
                            const float* __restrict__ Wg2, unsigned short* __restrict__ Wg2_t,
                            const int* __restrict__ batch, int* __restrict__ gptr,
                            float* __restrict__ logits, float* __restrict__ pooled,
                            const int* __restrict__ src, const int* __restrict__ dst,
                            int* __restrict__ cnt_s, int* __restrict__ cnt_d) {
    int id = blockIdx.x * blockDim.x + threadIdx.x;
    if (id < PREP_A) {
        int n = id >> 5, f = (id & 31) * 4;
        float4 v = *(const float4*)(x + (size_t)n * F_IN + f);
        ushort4 o; o.x = f2bf(v.x); o.y = f2bf(v.y); o.z = f2bf(v.z); o.w = f2bf(v.w);
        *(ushort4*)(tcat + (size_t)n * TC + f) = o;
        return;
    }
    id -= PREP_A;
    if (id < PREP_B) {
        int k = id % TC, n = id / TC;
        Wcb_t[(size_t)n * TC + k] = f2bf(Wcheb[(size_t)k * C1_DIM + n]);
        return;
    }
    id -= PREP_B;
    if (id < PREP_C) {
        int k = id % C1_DIM, n = id / C1_DIM;
        Wg1_t[(size_t)n * C1_DIM + k] = f2bf(Wg1[(size_t)k * C2_DIM + n]);
        return;
    }
    id -= PREP_C;
    if (id < PREP_D) {
        int k = id % C2_DIM, n = id / C2_DIM;
        Wg2_t[(size_t)n * C2_DIM + k] = f2bf(Wg2[(size_t)k * C3_DIM + n]);
        return;
    }
    id -= PREP_D;
    if (id < PREP_E) {
        int i = id;
        int b = batch[i];
        if (i == 0) { for (int g = 0; g <= b; g++) gptr[g] = 0; }
        else {
            int bp = batch[i - 1];
            for (int g = bp + 1; g <= b; g++) gptr[g] = i;
        }
        if (i == N_NODES - 1) { for (int g = b + 1; g <= N_GRAPHS; g++) gptr[g] = N_NODES; }
        return;
    }
    id -= PREP_E;
    if (id < PREP_F) { logits[id] = 0.0f; return; }
    id -= PREP_F;
    if (id < PREP_H) { pooled[id] = 0.0f; return; }
    id -= PREP_H;
    if (id < PREP_G) {   // guarded tail
        atomicAdd(&cnt_s[src[id]], 1);
        atomicAdd(&cnt_d[dst[id]], 1);
    }
}

// ---------- CSR fill with EMBEDDED per-block redundant scan (no scan stage) ----------
__global__ __launch_bounds__(256) void fill_scan_kernel(
        const int* __restrict__ src, const int* __restrict__ dst,
        const int* __restrict__ cnt_s, const int* __restrict__ cnt_d,
        int* __restrict__ rowptr, int* __restrict__ fillc,
        int2* __restrict__ ecb, int2* __restrict__ egc, int E, int n) {
    __shared__ int ldsc[N_NODES];
    __shared__ int sums[256];
    int tid = threadIdx.x;
    for (int i = tid; i < n; i += 256) ldsc[i] = cnt_d[i];
    __syncthreads();
    int chunk = (n + 255) / 256;
    int s0 = min(n, tid * chunk), s1 = min(n, s0 + chunk);
    int loc = 0;
    for (int i = s0; i < s1; i++) loc += ldsc[i];
    sums[tid] = loc;
    __syncthreads();
    for (int off = 1; off < 256; off <<= 1) {
        int t = (tid >= off) ? sums[tid - off] : 0;
        __syncthreads();
        sums[tid] += t;
        __syncthreads();
    }
    int pre = sums[tid] - loc;
    for (int i = s0; i < s1; i++) { int v = ldsc[i]; ldsc[i] = pre; pre += v; }
    __syncthreads();
    if (blockIdx.x == 0) {   // block 0 publishes rowptr for the gather kernels
        for (int i = tid; i < n; i += 256) rowptr[i] = ldsc[i];
        if (tid == 255) rowptr[n] = pre;
    }
    int e = blockIdx.x * 256 + tid;
    if (e >= E) return;
    int s = src[e], d = dst[e];
    int pos = ldsc[d] + atomicAdd(&fillc[d], 1);
    int cs = cnt_s[s], cd = cnt_s[d];
    float ds = (cs > 0) ? rsqrtf((float)cs) : 0.0f;
    float dd = (cd > 0) ? rsqrtf((float)cd) : 0.0f;
    float nr = rsqrtf((float)cnt_d[s] + 1.0f) * rsqrtf((float)cnt_d[d] + 1.0f);
    ecb[pos] = make_int2(s, __float_as_int(-(ds * dd)));
    egc[pos] = make_int2(s, __float_as_int(nr));
}

// ---------- Cheb gather over tcat slices ----------
// scalar-uniform edge pipeline: wave-uniform CSR row => v_readlane broadcast
// (no LDS pipe) + saddr-form gathers.
__global__ __launch_bounds__(256) void gather_cheb_bf(
        const unsigned short* __restrict__ tb, const int* __restrict__ rowptr,
        const int2* __restrict__ edges,
        const unsigned short* __restrict__ base, float alpha, float beta,
        unsigned short* __restrict__ outc, int n) {
    int w = (blockIdx.x * blockDim.x + threadIdx.x) >> 6;
    int lane = threadIdx.x & 63;
    if (w >= n) return;
    w = __builtin_amdgcn_readfirstlane(w);
    int rs = __builtin_amdgcn_readfirstlane(rowptr[w]);
    int re = __builtin_amdgcn_readfirstlane(rowptr[w + 1]);
    float a0 = 0.0f, a1 = 0.0f;
    for (int b = rs; b < re; b += 64) {
        int nv = min(64, re - b);
        int cl = 0, wlb = 0;
        if (b + lane < re) { int2 e = edges[b + lane]; cl = e.x; wlb = e.y; }
        int nk = (nv + 15) & ~15;   // pad lanes hold cl=0, w=0 (row 0 * 0 -> safe)
        for (int j = 0; j < nk; j += 16) {
            int ss[16]; float ww[16]; unsigned uu[16];
            #pragma unroll
            for (int q = 0; q < 16; q++) {
                ss[q] = __builtin_amdgcn_readlane(cl, j + q);
                ww[q] = __uint_as_float((unsigned)__builtin_amdgcn_readlane(wlb, j + q));
            }
            #pragma unroll
            for (int q = 0; q < 16; q++)
                uu[q] = *(const unsigned*)(tb + (size_t)ss[q] * TC + lane * 2);
            #pragma unroll
            for (int q = 0; q < 16; q++) { a0 += ww[q] * bf_lo(uu[q]); a1 += ww[q] * bf_hi(uu[q]); }
        }
    }
    if (base) {
        unsigned ub = ((const unsigned*)(base + (size_t)w * TC))[lane];
        a0 = alpha * a0 + beta * bf_lo(ub);
        a1 = alpha * a1 + beta * bf_hi(ub);
    } else {
        a0 *= alpha; a1 *= alpha;
    }
    ushort2 o; o.x = f2bf(a0); o.y = f2bf(a1);
    *(ushort2*)(outc + (size_t)w * TC + lane * 2) = o;
}

// ---------- bf16 MFMA GEMM from GLOBAL A (used for GEMM1) ----------
template<int JT, int KC>
__global__ __launch_bounds__(256) void gemm_bf16(
        const unsigned short* __restrict__ A, const unsigned short* __restrict__ Bt,
        const float* __restrict__ bias,
        unsigned short* __restrict__ Cb, int M, int N) {
    int m0 = blockIdx.y * 64, n0 = blockIdx.x * (JT * 32);
    int wave = threadIdx.x >> 6, lane = threadIdx.x & 63;
    int wm = (wave & 1) * 32, wn = (wave >> 1) * (JT * 16);
    int l15 = lane & 15, quad = lane >> 4;

    v4f acc[2][JT];
    #pragma unroll
    for (int i = 0; i < 2; i++)
        #pragma unroll
        for (int j = 0; j < JT; j++) acc[i][j] = (v4f){0.f, 0.f, 0.f, 0.f};

    const unsigned short* Ab[2]; bool av[2];
    #pragma unroll
    for (int i = 0; i < 2; i++) {
        int row = m0 + wm + i * 16 + l15;
        av[i] = row < M;
        Ab[i] = A + (size_t)(av[i] ? row : 0) * KC + quad * 8;
    }
    const unsigned short* Bb[JT];
    #pragma unroll
    for (int j = 0; j < JT; j++) {
        int coln = n0 + wn + j * 16 + l15;
        Bb[j] = Bt + (size_t)coln * KC + quad * 8;
    }
    const v8s zero8 = {0, 0, 0, 0, 0, 0, 0, 0};

    #pragma unroll
    for (int k0 = 0; k0 < KC; k0 += 32) {
        v8s a[2], b[JT];
        #pragma unroll
        for (int i = 0; i < 2; i++) a[i] = av[i] ? *(const v8s*)(Ab[i] + k0) : zero8;
        #pragma unroll
        for (int j = 0; j < JT; j++) b[j] = *(const v8s*)(Bb[j] + k0);
        #pragma unroll
        for (int i = 0; i < 2; i++)
            #pragma unroll
            for (int j = 0; j < JT; j++)
                acc[i][j] = __builtin_amdgcn_mfma_f32_16x16x32_bf16(a[i], b[j], acc[i][j], 0, 0, 0);
    }

    float bv[JT];
    #pragma unroll
    for (int j = 0; j < JT; j++) bv[j] = bias[n0 + wn + j * 16 + l15];
    #pragma unroll
    for (int i = 0; i < 2; i++) {
        #pragma unroll
        for (int r = 0; r < 4; r++) {
            int row = m0 + wm + i * 16 + quad * 4 + r;
            if (row >= M) continue;
            #pragma unroll
            for (int j = 0; j < JT; j++) {
                int coln = n0 + wn + j * 16 + l15;
                float v = fmaxf(acc[i][j][r] + bv[j], 0.0f);
                Cb[(size_t)row * N + coln] = f2bf(v);
            }
        }
    }
}

// ---------- FUSED GCN-aggregate + MFMA GEMM ----------
// R5: each block aggregates its OWN 64 A-rows into LDS (block-local -> legal
// fusion without grid sync), then MFMAs from LDS. Kills the z1b/z2b global
// round-trip and one dispatch boundary each. LDS A-tile XOR-swizzled
// (byte ^= (row&7)<<4, G4): A-frag ds_read_b128 2-way (free) instead of 16-way.
template<int JT, int KC>   // KC = K = input channels; FPL = KC/64 floats per lane
__global__ __launch_bounds__(256) void gemm_gcn_fused(
        const unsigned short* __restrict__ h_in,
        const int* __restrict__ rowptr, const int2* __restrict__ edges,
        const int* __restrict__ cnt_d,
        const unsigned short* __restrict__ Bt, const float* __restrict__ bias,
        unsigned short* __restrict__ Cb, const float* __restrict__ wg,
        float* __restrict__ logits, int M, int N) {
    constexpr int FPL = KC / 64;
    __shared__ unsigned short zt[64 * KC];   // 16KB (KC=128) / 32KB (KC=256)
    int m0 = blockIdx.y * 64, n0 = blockIdx.x * (JT * 32);
    int wave = threadIdx.x >> 6, lane = threadIdx.x & 63;

    // ---- gather phase: wave v aggregates rows m0+v*16 .. +15 into LDS ----
    for (int r = 0; r < 16; ++r) {
        int wl = wave * 16 + r;         // local row 0..63
        int w  = m0 + wl;               // global row
        float acc[FPL];
        #pragma unroll
        for (int q = 0; q < FPL; q++) acc[q] = 0.0f;
        if (w < M) {
            int rs = __builtin_amdgcn_readfirstlane(rowptr[w]);
            int re = __builtin_amdgcn_readfirstlane(rowptr[w + 1]);
            for (int b = rs; b < re; b += 64) {
                int cl = 0, wlb = 0;
                if (b + lane < re) { int2 e = edges[b + lane]; cl = e.x; wlb = e.y; }
                int nk = (min(64, re - b) + 15) & ~15;
                for (int j = 0; j < nk; j += 16) {
                    int ss[16]; float ww[16];
                    #pragma unroll
                    for (int q = 0; q < 16; q++) {
                        ss[q] = __builtin_amdgcn_readlane(cl, j + q);
                        ww[q] = __uint_as_float((unsigned)__builtin_amdgcn_readlane(wlb, j + q));
                    }
                    if constexpr (FPL == 2) {
                        unsigned uu[16];
                        #pragma unroll
                        for (int q = 0; q < 16; q++)
                            uu[q] = *(const unsigned*)(h_in + (size_t)ss[q] * KC + lane * 2);
                        #pragma unroll
                        for (int q = 0; q < 16; q++) { acc[0] += ww[q] * bf_lo(uu[q]); acc[1] += ww[q] * bf_hi(uu[q]); }
                    } else {
                        uint2 uu[16];
                        #pragma unroll
                        for (int q = 0; q < 16; q++)
                            uu[q] = *(const uint2*)(h_in + (size_t)ss[q] * KC + lane * 4);
                        #pragma unroll
                        for (int q = 0; q < 16; q++) {
                            acc[0] += ww[q] * bf_lo(uu[q].x); acc[1] += ww[q] * bf_hi(uu[q].x);
                            acc[2] += ww[q] * bf_lo(uu[q].y); acc[3] += ww[q] * bf_hi(uu[q].y);
                        }
                    }
                }
            }
            float sn = 1.0f / (float)(cnt_d[w] + 1);   // dinv^2 self-loop term
            if constexpr (FPL == 2) {
                unsigned u = *(const unsigned*)(h_in + (size_t)w * KC + lane * 2);
                acc[0] += sn * bf_lo(u); acc[1] += sn * bf_hi(u);
            } else {
                uint2 u = *(const uint2*)(h_in + (size_t)w * KC + lane * 4);
                acc[0] += sn * bf_lo(u.x); acc[1] += sn * bf_hi(u.x);
                acc[2] += sn * bf_lo(u.y); acc[3] += sn * bf_hi(u.y);
            }
        }
        // swizzled LDS write (row-contiguous, permuted 16B blocks: conflict-free)
        if constexpr (FPL == 2) {
            ushort2 o; o.x = f2bf(acc[0]); o.y = f2bf(acc[1]);
            unsigned col = (lane * 4u) ^ ((unsigned)(wl & 7) << 4);
            *(ushort2*)((char*)zt + (size_t)wl * (KC * 2) + col) = o;
        } else {
            ushort4 o; o.x = f2bf(acc[0]); o.y = f2bf(acc[1]);
            o.z = f2bf(acc[2]); o.w = f2bf(acc[3]);
            unsigned col = (lane * 8u) ^ ((unsigned)(wl & 7) << 4);
            *(ushort4*)((char*)zt + (size_t)wl * (KC * 2) + col) = o;
        }
    }
    __syncthreads();

    // ---- MFMA phase: A from swizzled LDS, B from global ----
    int wm = (wave & 1) * 32, wn = (wave >> 1) * (JT * 16);
    int l15 = lane & 15, quad = lane >> 4;

    v4f acc2[2][JT];
    #pragma unroll
    for (int i = 0; i < 2; i++)
        #pragma unroll
        for (int j = 0; j < JT; j++) acc2[i][j] = (v4f){0.f, 0.f, 0.f, 0.f};

    const unsigned short* Bb[JT];
    #pragma unroll
    for (int j = 0; j < JT; j++) {
        int coln = n0 + wn + j * 16 + l15;
        Bb[j] = Bt + (size_t)coln * KC + quad * 8;
    }

    #pragma unroll
    for (int k0 = 0; k0 < KC; k0 += 32) {
        v8s a[2], b[JT];
        #pragma unroll
        for (int i = 0; i < 2; i++) {
            int rowl = wm + i * 16 + l15;
            unsigned col = ((unsigned)(k0 * 2 + quad * 16)) ^ ((unsigned)(rowl & 7) << 4);
            a[i] = *(const v8s*)((const char*)zt + (size_t)rowl * (KC * 2) + col);
        }
        #pragma unroll
        for (int j = 0; j < JT; j++) b[j] = *(const v8s*)(Bb[j] + k0);
        #pragma unroll
        for (int i = 0; i < 2; i++)
            #pragma unroll
            for (int j = 0; j < JT; j++)
                acc2[i][j] = __builtin_amdgcn_mfma_f32_16x16x32_bf16(a[i], b[j], acc2[i][j], 0, 0, 0);
    }

    float bv[JT], wgj[JT];
    #pragma unroll
    for (int j = 0; j < JT; j++) {
        int coln = n0 + wn + j * 16 + l15;
        bv[j] = bias[coln];
        wgj[j] = wg ? wg[coln] : 0.0f;
    }
    #pragma unroll
    for (int i = 0; i < 2; i++) {
        #pragma unroll
        for (int r = 0; r < 4; r++) {
            int row = m0 + wm + i * 16 + quad * 4 + r;
            if (row >= M) continue;
            float gval = 0.0f;
            #pragma unroll
            for (int j = 0; j < JT; j++) {
                int coln = n0 + wn + j * 16 + l15;
                float v = fmaxf(acc2[i][j][r] + bv[j], 0.0f);
                Cb[(size_t)row * N + coln] = f2bf(v);
                gval += v * wgj[j];
            }
            if (wg) {
                #pragma unroll
                for (int off = 1; off < 16; off <<= 1) gval += __shfl_xor(gval, off);
                if (l15 == 0) atomicAdd(&logits[row], gval);
            }
        }
    }
}

// ---------- pool (G x 8 blocks, parallel) + last-block-done FC ----------
// R4 lesson: 64-block pool = 1.9% occupancy = 62us. Restore 512-block pool;
// the 8th finisher per graph runs the FC (one-shot fence, not a spin barrier).
__global__ __launch_bounds__(256) void pool_fc_kernel(
        const unsigned short* __restrict__ h3b,
        const float* __restrict__ logits, const int* __restrict__ gptr,
        float* __restrict__ pooled, int* __restrict__ pcnt,
        const float* __restrict__ Wfc, const float* __restrict__ bfc,
        float* __restrict__ out) {
    __shared__ float red[256];
    __shared__ float pl[C3_DIM];
    __shared__ int lastf;
    int g = blockIdx.x, sl = blockIdx.y, tid = threadIdx.x;
    int gs = gptr[g], ge = gptr[g + 1];
    float m = -INFINITY;
    for (int i = gs + tid; i < ge; i += 256) m = fmaxf(m, logits[i]);
    red[tid] = m; __syncthreads();
    for (int off = 128; off > 0; off >>= 1) {
        if (tid < off) red[tid] = fmaxf(red[tid], red[tid + off]);
        __syncthreads();
    }
    m = red[0]; __syncthreads();
    float s = 0.0f;
    for (int i = gs + tid; i < ge; i += 256) s += expf(logits[i] - m);
    red[tid] = s; __syncthreads();
    for (int off = 128; off > 0; off >>= 1) {
        if (tid < off) red[tid] += red[tid + off];
        __syncthreads();
    }
    s = red[0];
    float sinv = (s > 0.0f) ? 1.0f / s : 0.0f;
    int cnt = ge - gs;
    int i0 = gs + (cnt * sl) / 8;
    int i1 = gs + (cnt * (sl + 1)) / 8;
    float a0 = 0.0f, a1 = 0.0f;
    for (int i = i0; i < i1; i++) {
        float al = expf(logits[i] - m) * sinv;
        unsigned u = ((const unsigned*)(h3b + (size_t)i * C3_DIM))[tid];
        a0 += al * bf_lo(u);
        a1 += al * bf_hi(u);
    }
    if (i1 > i0) {
        atomicAdd(&pooled[(size_t)g * C3_DIM + tid * 2 + 0], a0);
        atomicAdd(&pooled[(size_t)g * C3_DIM + tid * 2 + 1], a1);
    }
    __syncthreads();                      // drains this block's atomics (vmcnt)
    if (tid == 0) {
        __threadfence();                  // release
        int old = atomicAdd(&pcnt[g], 1);
        lastf = (old == 7) ? 1 : 0;
    }
    __syncthreads();
    if (lastf) {                          // this is the 8th (last) block for g
        __threadfence();                  // acquire
        pl[tid * 2 + 0] = __hip_atomic_load(&pooled[(size_t)g * C3_DIM + tid * 2 + 0],
                                            __ATOMIC_RELAXED, __HIP_MEMORY_SCOPE_AGENT);
        pl[tid * 2 + 1] = __hip_atomic_load(&pooled[(size_t)g * C3_DIM + tid * 2 + 1],
                                            __ATOMIC_RELAXED, __HIP_MEMORY_SCOPE_AGENT);
        __syncthreads();
        if (tid < 64) {
            float acc = -INFINITY;
            if (tid < NCLS) {
                acc = bfc[tid];
                for (int k = 0; k < C3_DIM; k++)
                    acc += pl[k] * Wfc[k * NCLS + tid];
            }
            float mm = acc;
            #pragma unroll
            for (int off = 8; off > 0; off >>= 1) mm = fmaxf(mm, __shfl_xor(mm, off, 16));
            float e = (tid < NCLS) ? expf(acc - mm) : 0.0f;
            float ss = e;
            #pragma unroll
            for (int off = 8; off > 0; off >>= 1) ss += __shfl_xor(ss, off, 16);
            if (tid < NCLS) out[g * NCLS + tid] = acc - mm - logf(ss);
        }
    }
}

// ---------- host ----------
extern "C" void kernel_launch(void* const* d_in, const int* in_sizes, int n_in,
                              void* d_out, int out_size, void* d_ws, size_t ws_size,
                              hipStream_t stream) {
    const float* x      = (const float*)d_in[0];
    const int*   ei     = (const int*)d_in[1];
    const int*   batch  = (const int*)d_in[2];
    const float* W_cheb = (const float*)d_in[3];
    const float* b_cheb = (const float*)d_in[4];
    const float* W_g1   = (const float*)d_in[5];
    const float* b_g1   = (const float*)d_in[6];
    const float* W_g2   = (const float*)d_in[7];
    const float* b_g2   = (const float*)d_in[8];
    const float* w_gate = (const float*)d_in[9];
    const float* W_fc   = (const float*)d_in[11];
    const float* b_fc   = (const float*)d_in[12];
    const int* src = ei;
    const int* dst = ei + N_EDGES;
    float* out = (float*)d_out;

    const int N = N_NODES, E = N_EDGES, G = N_GRAPHS;

    char* Wp = (char*)d_ws;
    auto alloc = [&](size_t bytes) {
        void* p = Wp;
        Wp += (bytes + 255) & ~(size_t)255;
        return p;
    };
    int*   cnt3    = (int*)alloc(((size_t)3 * N + G) * 4);  // cnt_s | cnt_d | fillc | pcnt
    int*   cnt_s   = cnt3;
    int*   cnt_d   = cnt3 + N;
    int*   fillc   = cnt3 + 2 * N;
    int*   pcnt    = cnt3 + 3 * N;
    int*   rowptr  = (int*)alloc((N + 1) * 4);
    int2*  ecb     = (int2*)alloc((size_t)E * 8);
    int2*  egc     = (int2*)alloc((size_t)E * 8);
    unsigned short* tcat  = (unsigned short*)alloc((size_t)N * TC * 2);
    unsigned short* h1b   = (unsigned short*)alloc((size_t)N * C1_DIM * 2);
    unsigned short* h2b   = (unsigned short*)alloc((size_t)N * C2_DIM * 2);
    unsigned short* h3b   = (unsigned short*)alloc((size_t)N * C3_DIM * 2);
    unsigned short* Wcb_t = (unsigned short*)alloc((size_t)TC * C1_DIM * 2);
    unsigned short* Wg1_t = (unsigned short*)alloc((size_t)C1_DIM * C2_DIM * 2);
    unsigned short* Wg2_t = (unsigned short*)alloc((size_t)C2_DIM * C3_DIM * 2);
    float* logits  = (float*)alloc(N * 4);
    int*   gptr    = (int*)alloc((G + 1) * 4);
    float* pooled  = (float*)alloc((size_t)G * C3_DIM * 4);

    dim3 blk(256);
    auto cdiv = [](int a, int b) { return (a + b - 1) / b; };

    // --- memset counters (+pcnt), fused prep ---
    hipMemsetAsync(cnt3, 0, ((size_t)3 * N + G) * sizeof(int), stream);
    hipLaunchKernelGGL(prep_kernel, dim3(cdiv(PREP_TOTAL, 256)), blk, 0, stream,
                       x, tcat, W_cheb, Wcb_t, W_g1, Wg1_t, W_g2, Wg2_t,
                       batch, gptr, logits, pooled, src, dst, cnt_s, cnt_d);

    // --- CSR fill with embedded redundant scan ---
    hipLaunchKernelGGL(fill_scan_kernel, dim3(cdiv(E, 256)), blk, 0, stream,
                       src, dst, cnt_s, cnt_d, rowptr, fillc, ecb, egc, E, N);

    const int NWB = cdiv(N, 4);   // cheb gathers: 4 waves/block, 1 node/wave

    // --- Cheb recurrence on tcat slices ---
    hipLaunchKernelGGL(gather_cheb_bf, dim3(NWB), blk, 0, stream,
                       tcat + 0 * F_IN, rowptr, ecb,
                       (const unsigned short*)nullptr, 1.0f, 0.0f, tcat + 1 * F_IN, N);
    hipLaunchKernelGGL(gather_cheb_bf, dim3(NWB), blk, 0, stream,
                       tcat + 1 * F_IN, rowptr, ecb,
                       tcat + 0 * F_IN, 2.0f, -1.0f, tcat + 2 * F_IN, N);
    hipLaunchKernelGGL(gather_cheb_bf, dim3(NWB), blk, 0, stream,
                       tcat + 2 * F_IN, rowptr, ecb,
                       tcat + 1 * F_IN, 2.0f, -1.0f, tcat + 3 * F_IN, N);
    hipLaunchKernelGGL(gather_cheb_bf, dim3(NWB), blk, 0, stream,
                       tcat + 3 * F_IN, rowptr, ecb,
                       tcat + 2 * F_IN, 2.0f, -1.0f, tcat + 4 * F_IN, N);

    // --- GEMM1: h1 = relu(Tcat @ Wcb^T + b)  K=640 ---
    hipLaunchKernelGGL((gemm_bf16<2, TC>), dim3(C1_DIM / 64, cdiv(N, 64)), blk, 0, stream,
                       tcat, Wcb_t, b_cheb, h1b, N, C1_DIM);

    // --- fused GCN1-aggregate + GEMM2 (K=128, block tile 64x128, grid (2,157)) ---
    hipLaunchKernelGGL((gemm_gcn_fused<4, C1_DIM>), dim3(C2_DIM / 128, cdiv(N, 64)), blk, 0, stream,
                       h1b, rowptr, egc, cnt_d, Wg1_t, b_g1, h2b,
                       (const float*)nullptr, (float*)nullptr, N, C2_DIM);

    // --- fused GCN2-aggregate + GEMM3 (K=256, block tile 64x256, grid (2,157)) + gate dot ---
    hipLaunchKernelGGL((gemm_gcn_fused<8, C2_DIM>), dim3(C3_DIM / 256, cdiv(N, 64)), blk, 0, stream,
                       h2b, rowptr, egc, cnt_d, Wg2_t, b_g2, h3b,
                       w_gate, logits, N, C3_DIM);

    // --- pool (G x 8, parallel) + last-block FC ---
    hipLaunchKernelGGL(pool_fc_kernel, dim3(G, 8), blk, 0, stream,
                       h3b, logits, gptr, pooled, pcnt, W_fc, b_fc, out);
}

// Round 6
// 267.646 us; speedup vs baseline: 1.1946x; 1.1946x over previous
//
#include <hip/hip_runtime.h>
#include <hip/hip_bf16.h>
#include <math.h>

#define N_NODES 10000
#define N_EDGES 160000
#define N_GRAPHS 64
#define F_IN    128
#define C1_DIM  128
#define C2_DIM  256
#define C3_DIM  512
#define K_CHEB  5
#define NCLS    10
#define TC      (K_CHEB * F_IN)    // 640

typedef short v8s __attribute__((ext_vector_type(8)));
typedef float v4f __attribute__((ext_vector_type(4)));

// ---------- bf16 helpers ----------
static __device__ __forceinline__ unsigned short f2bf(float f) {
    unsigned u = __float_as_uint(f);
    unsigned r = (u + 0x7FFFu + ((u >> 16) & 1u)) >> 16;   // RNE
    return (unsigned short)r;
}
static __device__ __forceinline__ float bf_lo(unsigned u) { return __uint_as_float(u << 16); }
static __device__ __forceinline__ float bf_hi(unsigned u) { return __uint_as_float(u & 0xFFFF0000u); }

// ---------- session constraints (counter-evidenced) ----------
// R2/R3: grid-wide sync fusion DEAD (cg ~100us/sync; custom barrier worse).
// R4: pool at 64 blocks DEAD (1.9% occupancy, 62us).
// R5: SpMM-gather fused into GEMM DEAD (314 blocks x 16 serial rows/wave,
//     latency-bound, 67us vs ~25us split). Gathers need node-level wave grid.
// => R1 13-dispatch structure + pool/fc last-arriver merge only.

// ---------- fused prep ----------
#define PREP_A (N_NODES * 32)            // x conv, 4 floats per item
#define PREP_B (TC * C1_DIM)             // W_cheb transpose (write-coalesced)
#define PREP_C (C1_DIM * C2_DIM)         // W_g1
#define PREP_D (C2_DIM * C3_DIM)         // W_g2
#define PREP_E N_NODES                   // gptr
#define PREP_F N_NODES                   // zero logits
#define PREP_H (N_GRAPHS * C3_DIM)       // zero pooled
#define PREP_G N_EDGES                   // degree count (guarded tail)
#define PREP_TOTAL (PREP_A + PREP_B + PREP_C + PREP_D + PREP_E + PREP_F + PREP_H + PREP_G)
__global__ void prep_kernel(const float* __restrict__ x, unsigned short* __restrict__ tcat,
                            const float* __restrict__ Wcheb, unsigned short* __restrict__ Wcb_t,
                            const float* __restrict__ Wg1, unsigned short* __restrict__ Wg1_t,
                            const float* __restrict__ Wg2, unsigned short* __restrict__ Wg2_t,
                            const int* __restrict__ batch, int* __restrict__ gptr,
                            float* __restrict__ logits, float* __restrict__ pooled,
                            const int* __restrict__ src, const int* __restrict__ dst,
                            int* __restrict__ cnt_s, int* __restrict__ cnt_d) {
    int id = blockIdx.x * blockDim.x + threadIdx.x;
    if (id < PREP_A) {
        int n = id >> 5, f = (id & 31) * 4;
        float4 v = *(const float4*)(x + (size_t)n * F_IN + f);
        ushort4 o; o.x = f2bf(v.x); o.y = f2bf(v.y); o.z = f2bf(v.z); o.w = f2bf(v.w);
        *(ushort4*)(tcat + (size_t)n * TC + f) = o;
        return;
    }
    id -= PREP_A;
    if (id < PREP_B) {
        int k = id % TC, n = id / TC;
        Wcb_t[(size_t)n * TC + k] = f2bf(Wcheb[(size_t)k * C1_DIM + n]);
        return;
    }
    id -= PREP_B;
    if (id < PREP_C) {
        int k = id % C1_DIM, n = id / C1_DIM;
        Wg1_t[(size_t)n * C1_DIM + k] = f2bf(Wg1[(size_t)k * C2_DIM + n]);
        return;
    }
    id -= PREP_C;
    if (id < PREP_D) {
        int k = id % C2_DIM, n = id / C2_DIM;
        Wg2_t[(size_t)n * C2_DIM + k] = f2bf(Wg2[(size_t)k * C3_DIM + n]);
        return;
    }
    id -= PREP_D;
    if (id < PREP_E) {
        int i = id;
        int b = batch[i];
        if (i == 0) { for (int g = 0; g <= b; g++) gptr[g] = 0; }
        else {
            int bp = batch[i - 1];
            for (int g = bp + 1; g <= b; g++) gptr[g] = i;
        }
        if (i == N_NODES - 1) { for (int g = b + 1; g <= N_GRAPHS; g++) gptr[g] = N_NODES; }
        return;
    }
    id -= PREP_E;
    if (id < PREP_F) { logits[id] = 0.0f; return; }
    id -= PREP_F;
    if (id < PREP_H) { pooled[id] = 0.0f; return; }
    id -= PREP_H;
    if (id < PREP_G) {   // guarded tail
        atomicAdd(&cnt_s[src[id]], 1);
        atomicAdd(&cnt_d[dst[id]], 1);
    }
}

// ---------- CSR fill with EMBEDDED per-block redundant scan (no scan stage) ----------
__global__ __launch_bounds__(256) void fill_scan_kernel(
        const int* __restrict__ src, const int* __restrict__ dst,
        const int* __restrict__ cnt_s, const int* __restrict__ cnt_d,
        int* __restrict__ rowptr, int* __restrict__ fillc,
        int2* __restrict__ ecb, int2* __restrict__ egc, int E, int n) {
    __shared__ int ldsc[N_NODES];
    __shared__ int sums[256];
    int tid = threadIdx.x;
    for (int i = tid; i < n; i += 256) ldsc[i] = cnt_d[i];
    __syncthreads();
    int chunk = (n + 255) / 256;
    int s0 = min(n, tid * chunk), s1 = min(n, s0 + chunk);
    int loc = 0;
    for (int i = s0; i < s1; i++) loc += ldsc[i];
    sums[tid] = loc;
    __syncthreads();
    for (int off = 1; off < 256; off <<= 1) {
        int t = (tid >= off) ? sums[tid - off] : 0;
        __syncthreads();
        sums[tid] += t;
        __syncthreads();
    }
    int pre = sums[tid] - loc;
    for (int i = s0; i < s1; i++) { int v = ldsc[i]; ldsc[i] = pre; pre += v; }
    __syncthreads();
    if (blockIdx.x == 0) {   // block 0 publishes rowptr for the gather kernels
        for (int i = tid; i < n; i += 256) rowptr[i] = ldsc[i];
        if (tid == 255) rowptr[n] = pre;
    }
    int e = blockIdx.x * 256 + tid;
    if (e >= E) return;
    int s = src[e], d = dst[e];
    int pos = ldsc[d] + atomicAdd(&fillc[d], 1);
    int cs = cnt_s[s], cd = cnt_s[d];
    float ds = (cs > 0) ? rsqrtf((float)cs) : 0.0f;
    float dd = (cd > 0) ? rsqrtf((float)cd) : 0.0f;
    float nr = rsqrtf((float)cnt_d[s] + 1.0f) * rsqrtf((float)cnt_d[d] + 1.0f);
    ecb[pos] = make_int2(s, __float_as_int(-(ds * dd)));
    egc[pos] = make_int2(s, __float_as_int(nr));
}

// ---------- Cheb gather over tcat slices (scalar-uniform edge pipeline) ----------
__global__ __launch_bounds__(256) void gather_cheb_bf(
        const unsigned short* __restrict__ tb, const int* __restrict__ rowptr,
        const int2* __restrict__ edges,
        const unsigned short* __restrict__ base, float alpha, float beta,
        unsigned short* __restrict__ outc, int n) {
    int w = (blockIdx.x * blockDim.x + threadIdx.x) >> 6;
    int lane = threadIdx.x & 63;
    if (w >= n) return;
    w = __builtin_amdgcn_readfirstlane(w);
    int rs = __builtin_amdgcn_readfirstlane(rowptr[w]);
    int re = __builtin_amdgcn_readfirstlane(rowptr[w + 1]);
    float a0 = 0.0f, a1 = 0.0f;
    for (int b = rs; b < re; b += 64) {
        int nv = min(64, re - b);
        int cl = 0, wlb = 0;
        if (b + lane < re) { int2 e = edges[b + lane]; cl = e.x; wlb = e.y; }
        int nk = (nv + 15) & ~15;   // pad lanes hold cl=0, w=0 (row 0 * 0 -> safe)
        for (int j = 0; j < nk; j += 16) {
            int ss[16]; float ww[16]; unsigned uu[16];
            #pragma unroll
            for (int q = 0; q < 16; q++) {
                ss[q] = __builtin_amdgcn_readlane(cl, j + q);
                ww[q] = __uint_as_float((unsigned)__builtin_amdgcn_readlane(wlb, j + q));
            }
            #pragma unroll
            for (int q = 0; q < 16; q++)
                uu[q] = *(const unsigned*)(tb + (size_t)ss[q] * TC + lane * 2);
            #pragma unroll
            for (int q = 0; q < 16; q++) { a0 += ww[q] * bf_lo(uu[q]); a1 += ww[q] * bf_hi(uu[q]); }
        }
    }
    if (base) {
        unsigned ub = ((const unsigned*)(base + (size_t)w * TC))[lane];
        a0 = alpha * a0 + beta * bf_lo(ub);
        a1 = alpha * a1 + beta * bf_hi(ub);
    } else {
        a0 *= alpha; a1 *= alpha;
    }
    ushort2 o; o.x = f2bf(a0); o.y = f2bf(a1);
    *(ushort2*)(outc + (size_t)w * TC + lane * 2) = o;
}

// ---------- GCN pre-aggregation, scalar-uniform edge pipeline ----------
template<int FPL>   // C = FPL*64, FPL in {2,4}
__global__ __launch_bounds__(256) void gather_gcn_pre(
        const unsigned short* __restrict__ tb, const int* __restrict__ rowptr,
        const int2* __restrict__ edges,
        const int* __restrict__ cnt_d, unsigned short* __restrict__ z, int n) {
    const int C = FPL * 64;
    int w = (blockIdx.x * blockDim.x + threadIdx.x) >> 6;
    int lane = threadIdx.x & 63;
    if (w >= n) return;
    w = __builtin_amdgcn_readfirstlane(w);
    int rs = __builtin_amdgcn_readfirstlane(rowptr[w]);
    int re = __builtin_amdgcn_readfirstlane(rowptr[w + 1]);
    float acc[FPL];
    #pragma unroll
    for (int q = 0; q < FPL; q++) acc[q] = 0.0f;
    for (int b = rs; b < re; b += 64) {
        int nv = min(64, re - b);
        int cl = 0, wlb = 0;
        if (b + lane < re) { int2 e = edges[b + lane]; cl = e.x; wlb = e.y; }
        int nk = (nv + 15) & ~15;
        for (int j = 0; j < nk; j += 16) {
            int ss[16]; float ww[16];
            #pragma unroll
            for (int q = 0; q < 16; q++) {
                ss[q] = __builtin_amdgcn_readlane(cl, j + q);
                ww[q] = __uint_as_float((unsigned)__builtin_amdgcn_readlane(wlb, j + q));
            }
            if constexpr (FPL == 2) {
                unsigned uu[16];
                #pragma unroll
                for (int q = 0; q < 16; q++)
                    uu[q] = *(const unsigned*)(tb + (size_t)ss[q] * C + lane * 2);
                #pragma unroll
                for (int q = 0; q < 16; q++) { acc[0] += ww[q] * bf_lo(uu[q]); acc[1] += ww[q] * bf_hi(uu[q]); }
            } else {
                uint2 uu[16];
                #pragma unroll
                for (int q = 0; q < 16; q++)
                    uu[q] = *(const uint2*)(tb + (size_t)ss[q] * C + lane * 4);
                #pragma unroll
                for (int q = 0; q < 16; q++) {
                    acc[0] += ww[q] * bf_lo(uu[q].x); acc[1] += ww[q] * bf_hi(uu[q].x);
                    acc[2] += ww[q] * bf_lo(uu[q].y); acc[3] += ww[q] * bf_hi(uu[q].y);
                }
            }
        }
    }
    float sn = 1.0f / (float)(cnt_d[w] + 1);   // dinv^2 self-loop term
    if constexpr (FPL == 2) {
        unsigned u = ((const unsigned*)(tb + (size_t)w * C))[lane];
        acc[0] += sn * bf_lo(u); acc[1] += sn * bf_hi(u);
        ushort2 o; o.x = f2bf(acc[0]); o.y = f2bf(acc[1]);
        *(ushort2*)(z + (size_t)w * C + lane * 2) = o;
    } else {
        uint2 u = ((const uint2*)(tb + (size_t)w * C))[lane];
        acc[0] += sn * bf_lo(u.x); acc[1] += sn * bf_hi(u.x);
        acc[2] += sn * bf_lo(u.y); acc[3] += sn * bf_hi(u.y);
        ushort4 o; o.x = f2bf(acc[0]); o.y = f2bf(acc[1]);
        o.z = f2bf(acc[2]); o.w = f2bf(acc[3]);
        *(ushort4*)(z + (size_t)w * C + lane * 4) = o;
    }
}

// ---------- bf16 MFMA GEMM, compile-time K ----------
template<int JT, int KC>
__global__ __launch_bounds__(256) void gemm_bf16(
        const unsigned short* __restrict__ A, const unsigned short* __restrict__ Bt,
        const float* __restrict__ bias,
        unsigned short* __restrict__ Cb, const float* __restrict__ wg,
        float* __restrict__ logits, int M, int N) {
    int m0 = blockIdx.y * 64, n0 = blockIdx.x * (JT * 32);
    int wave = threadIdx.x >> 6, lane = threadIdx.x & 63;
    int wm = (wave & 1) * 32, wn = (wave >> 1) * (JT * 16);
    int l15 = lane & 15, quad = lane >> 4;

    v4f acc[2][JT];
    #pragma unroll
    for (int i = 0; i < 2; i++)
        #pragma unroll
        for (int j = 0; j < JT; j++) acc[i][j] = (v4f){0.f, 0.f, 0.f, 0.f};

    const unsigned short* Ab[2]; bool av[2];
    #pragma unroll
    for (int i = 0; i < 2; i++) {
        int row = m0 + wm + i * 16 + l15;
        av[i] = row < M;
        Ab[i] = A + (size_t)(av[i] ? row : 0) * KC + quad * 8;
    }
    const unsigned short* Bb[JT];
    #pragma unroll
    for (int j = 0; j < JT; j++) {
        int coln = n0 + wn + j * 16 + l15;
        Bb[j] = Bt + (size_t)coln * KC + quad * 8;
    }
    const v8s zero8 = {0, 0, 0, 0, 0, 0, 0, 0};

    #pragma unroll
    for (int k0 = 0; k0 < KC; k0 += 32) {
        v8s a[2], b[JT];
        #pragma unroll
        for (int i = 0; i < 2; i++) a[i] = av[i] ? *(const v8s*)(Ab[i] + k0) : zero8;
        #pragma unroll
        for (int j = 0; j < JT; j++) b[j] = *(const v8s*)(Bb[j] + k0);
        #pragma unroll
        for (int i = 0; i < 2; i++)
            #pragma unroll
            for (int j = 0; j < JT; j++)
                acc[i][j] = __builtin_amdgcn_mfma_f32_16x16x32_bf16(a[i], b[j], acc[i][j], 0, 0, 0);
    }

    float bv[JT], wgj[JT];
    #pragma unroll
    for (int j = 0; j < JT; j++) {
        int coln = n0 + wn + j * 16 + l15;
        bv[j] = bias[coln];
        wgj[j] = wg ? wg[coln] : 0.0f;
    }
    #pragma unroll
    for (int i = 0; i < 2; i++) {
        #pragma unroll
        for (int r = 0; r < 4; r++) {
            int row = m0 + wm + i * 16 + quad * 4 + r;
            if (row >= M) continue;
            float gval = 0.0f;
            #pragma unroll
            for (int j = 0; j < JT; j++) {
                int coln = n0 + wn + j * 16 + l15;
                float v = fmaxf(acc[i][j][r] + bv[j], 0.0f);
                Cb[(size_t)row * N + coln] = f2bf(v);
                gval += v * wgj[j];
            }
            if (wg) {
                #pragma unroll
                for (int off = 1; off < 16; off <<= 1) gval += __shfl_xor(gval, off);
                if (l15 == 0) atomicAdd(&logits[row], gval);
            }
        }
    }
}

// ---------- pool (G x 8 blocks, parallel) + last-arriver FC ----------
__global__ __launch_bounds__(256) void pool_fc_kernel(
        const unsigned short* __restrict__ h3b,
        const float* __restrict__ logits, const int* __restrict__ gptr,
        float* __restrict__ pooled, int* __restrict__ pcnt,
        const float* __restrict__ Wfc, const float* __restrict__ bfc,
        float* __restrict__ out) {
    __shared__ float red[256];
    __shared__ float pl[C3_DIM];
    __shared__ int lastf;
    int g = blockIdx.x, sl = blockIdx.y, tid = threadIdx.x;
    int gs = gptr[g], ge = gptr[g + 1];
    float m = -INFINITY;
    for (int i = gs + tid; i < ge; i += 256) m = fmaxf(m, logits[i]);
    red[tid] = m; __syncthreads();
    for (int off = 128; off > 0; off >>= 1) {
        if (tid < off) red[tid] = fmaxf(red[tid], red[tid + off]);
        __syncthreads();
    }
    m = red[0]; __syncthreads();
    float s = 0.0f;
    for (int i = gs + tid; i < ge; i += 256) s += expf(logits[i] - m);
    red[tid] = s; __syncthreads();
    for (int off = 128; off > 0; off >>= 1) {
        if (tid < off) red[tid] += red[tid + off];
        __syncthreads();
    }
    s = red[0];
    float sinv = (s > 0.0f) ? 1.0f / s : 0.0f;
    int cnt = ge - gs;
    int i0 = gs + (cnt * sl) / 8;
    int i1 = gs + (cnt * (sl + 1)) / 8;
    float a0 = 0.0f, a1 = 0.0f;
    for (int i = i0; i < i1; i++) {
        float al = expf(logits[i] - m) * sinv;
        unsigned u = ((const unsigned*)(h3b + (size_t)i * C3_DIM))[tid];
        a0 += al * bf_lo(u);
        a1 += al * bf_hi(u);
    }
    if (i1 > i0) {
        atomicAdd(&pooled[(size_t)g * C3_DIM + tid * 2 + 0], a0);
        atomicAdd(&pooled[(size_t)g * C3_DIM + tid * 2 + 1], a1);
    }
    __syncthreads();                      // drains this block's atomics
    if (tid == 0) {
        __threadfence();                  // release
        int old = atomicAdd(&pcnt[g], 1);
        lastf = (old == 7) ? 1 : 0;
    }
    __syncthreads();
    if (lastf) {                          // 8th (last) block for g runs the FC
        __threadfence();                  // acquire
        pl[tid * 2 + 0] = __hip_atomic_load(&pooled[(size_t)g * C3_DIM + tid * 2 + 0],
                                            __ATOMIC_RELAXED, __HIP_MEMORY_SCOPE_AGENT);
        pl[tid * 2 + 1] = __hip_atomic_load(&pooled[(size_t)g * C3_DIM + tid * 2 + 1],
                                            __ATOMIC_RELAXED, __HIP_MEMORY_SCOPE_AGENT);
        __syncthreads();
        if (tid < 64) {
            float acc = -INFINITY;
            if (tid < NCLS) {
                acc = bfc[tid];
                for (int k = 0; k < C3_DIM; k++)
                    acc += pl[k] * Wfc[k * NCLS + tid];
            }
            float mm = acc;
            #pragma unroll
            for (int off = 8; off > 0; off >>= 1) mm = fmaxf(mm, __shfl_xor(mm, off, 16));
            float e = (tid < NCLS) ? expf(acc - mm) : 0.0f;
            float ss = e;
            #pragma unroll
            for (int off = 8; off > 0; off >>= 1) ss += __shfl_xor(ss, off, 16);
            if (tid < NCLS) out[g * NCLS + tid] = acc - mm - logf(ss);
        }
    }
}

// ---------- host ----------
extern "C" void kernel_launch(void* const* d_in, const int* in_sizes, int n_in,
                              void* d_out, int out_size, void* d_ws, size_t ws_size,
                              hipStream_t stream) {
    const float* x      = (const float*)d_in[0];
    const int*   ei     = (const int*)d_in[1];
    const int*   batch  = (const int*)d_in[2];
    const float* W_cheb = (const float*)d_in[3];
    const float* b_cheb = (const float*)d_in[4];
    const float* W_g1   = (const float*)d_in[5];
    const float* b_g1   = (const float*)d_in[6];
    const float* W_g2   = (const float*)d_in[7];
    const float* b_g2   = (const float*)d_in[8];
    const float* w_gate = (const float*)d_in[9];
    const float* W_fc   = (const float*)d_in[11];
    const float* b_fc   = (const float*)d_in[12];
    const int* src = ei;
    const int* dst = ei + N_EDGES;
    float* out = (float*)d_out;

    const int N = N_NODES, E = N_EDGES, G = N_GRAPHS;

    char* Wp = (char*)d_ws;
    auto alloc = [&](size_t bytes) {
        void* p = Wp;
        Wp += (bytes + 255) & ~(size_t)255;
        return p;
    };
    int*   cnt3    = (int*)alloc(((size_t)3 * N + G) * 4);  // cnt_s | cnt_d | fillc | pcnt
    int*   cnt_s   = cnt3;
    int*   cnt_d   = cnt3 + N;
    int*   fillc   = cnt3 + 2 * N;
    int*   pcnt    = cnt3 + 3 * N;
    int*   rowptr  = (int*)alloc((N + 1) * 4);
    int2*  ecb     = (int2*)alloc((size_t)E * 8);
    int2*  egc     = (int2*)alloc((size_t)E * 8);
    unsigned short* tcat  = (unsigned short*)alloc((size_t)N * TC * 2);
    unsigned short* h1b   = (unsigned short*)alloc((size_t)N * C1_DIM * 2);
    unsigned short* z1b   = (unsigned short*)alloc((size_t)N * C1_DIM * 2);
    unsigned short* h2b   = (unsigned short*)alloc((size_t)N * C2_DIM * 2);
    unsigned short* z2b   = (unsigned short*)alloc((size_t)N * C2_DIM * 2);
    unsigned short* h3b   = (unsigned short*)alloc((size_t)N * C3_DIM * 2);
    unsigned short* Wcb_t = (unsigned short*)alloc((size_t)TC * C1_DIM * 2);
    unsigned short* Wg1_t = (unsigned short*)alloc((size_t)C1_DIM * C2_DIM * 2);
    unsigned short* Wg2_t = (unsigned short*)alloc((size_t)C2_DIM * C3_DIM * 2);
    float* logits  = (float*)alloc(N * 4);
    int*   gptr    = (int*)alloc((G + 1) * 4);
    float* pooled  = (float*)alloc((size_t)G * C3_DIM * 4);

    dim3 blk(256);
    auto cdiv = [](int a, int b) { return (a + b - 1) / b; };

    // --- memset counters (+pcnt), fused prep ---
    hipMemsetAsync(cnt3, 0, ((size_t)3 * N + G) * sizeof(int), stream);
    hipLaunchKernelGGL(prep_kernel, dim3(cdiv(PREP_TOTAL, 256)), blk, 0, stream,
                       x, tcat, W_cheb, Wcb_t, W_g1, Wg1_t, W_g2, Wg2_t,
                       batch, gptr, logits, pooled, src, dst, cnt_s, cnt_d);

    // --- CSR fill with embedded redundant scan (scan stage eliminated) ---
    hipLaunchKernelGGL(fill_scan_kernel, dim3(cdiv(E, 256)), blk, 0, stream,
                       src, dst, cnt_s, cnt_d, rowptr, fillc, ecb, egc, E, N);

    const int NWB = cdiv(N, 4);   // gathers: 4 waves/block, 1 node/wave

    // --- Cheb recurrence on tcat slices ---
    hipLaunchKernelGGL(gather_cheb_bf, dim3(NWB), blk, 0, stream,
                       tcat + 0 * F_IN, rowptr, ecb,
                       (const unsigned short*)nullptr, 1.0f, 0.0f, tcat + 1 * F_IN, N);
    hipLaunchKernelGGL(gather_cheb_bf, dim3(NWB), blk, 0, stream,
                       tcat + 1 * F_IN, rowptr, ecb,
                       tcat + 0 * F_IN, 2.0f, -1.0f, tcat + 2 * F_IN, N);
    hipLaunchKernelGGL(gather_cheb_bf, dim3(NWB), blk, 0, stream,
                       tcat + 2 * F_IN, rowptr, ecb,
                       tcat + 1 * F_IN, 2.0f, -1.0f, tcat + 3 * F_IN, N);
    hipLaunchKernelGGL(gather_cheb_bf, dim3(NWB), blk, 0, stream,
                       tcat + 3 * F_IN, rowptr, ecb,
                       tcat + 2 * F_IN, 2.0f, -1.0f, tcat + 4 * F_IN, N);

    // --- GEMM1: h1 = relu(Tcat @ Wcb^T + b)  K=640 ---
    hipLaunchKernelGGL((gemm_bf16<2, TC>), dim3(C1_DIM / 64, cdiv(N, 64)), blk, 0, stream,
                       tcat, Wcb_t, b_cheb, h1b,
                       (const float*)nullptr, (float*)nullptr, N, C1_DIM);

    // --- GCN1 aggregate + GEMM2 (K=128) ---
    hipLaunchKernelGGL(gather_gcn_pre<2>, dim3(NWB), blk, 0, stream,
                       h1b, rowptr, egc, cnt_d, z1b, N);
    hipLaunchKernelGGL((gemm_bf16<4, C1_DIM>), dim3(C2_DIM / 128, cdiv(N, 64)), blk, 0, stream,
                       z1b, Wg1_t, b_g1, h2b,
                       (const float*)nullptr, (float*)nullptr, N, C2_DIM);

    // --- GCN2 aggregate + GEMM3 (K=256) + fused gate dot ---
    hipLaunchKernelGGL(gather_gcn_pre<4>, dim3(NWB), blk, 0, stream,
                       h2b, rowptr, egc, cnt_d, z2b, N);
    hipLaunchKernelGGL((gemm_bf16<4, C2_DIM>), dim3(C3_DIM / 128, cdiv(N, 64)), blk, 0, stream,
                       z2b, Wg2_t, b_g2, h3b,
                       w_gate, logits, N, C3_DIM);

    // --- pool (G x 8, parallel) + last-arriver FC ---
    hipLaunchKernelGGL(pool_fc_kernel, dim3(G, 8), blk, 0, stream,
                       h3b, logits, gptr, pooled, pcnt, W_fc, b_fc, out);
}

// Round 7
// 257.286 us; speedup vs baseline: 1.2427x; 1.0403x over previous
//
#include <hip/hip_runtime.h>
#include <hip/hip_bf16.h>
#include <math.h>

#define N_NODES 10000
#define N_EDGES 160000
#define N_GRAPHS 64
#define F_IN    128
#define C1_DIM  128
#define C2_DIM  256
#define C3_DIM  512
#define K_CHEB  5
#define NCLS    10
#define TC      (K_CHEB * F_IN)    // 640
#define PSL     16                 // pool slices per graph

typedef short v8s __attribute__((ext_vector_type(8)));
typedef float v4f __attribute__((ext_vector_type(4)));

// ---------- bf16 helpers ----------
static __device__ __forceinline__ unsigned short f2bf(float f) {
    unsigned u = __float_as_uint(f);
    unsigned r = (u + 0x7FFFu + ((u >> 16) & 1u)) >> 16;   // RNE
    return (unsigned short)r;
}
static __device__ __forceinline__ float bf_lo(unsigned u) { return __uint_as_float(u << 16); }
static __device__ __forceinline__ float bf_hi(unsigned u) { return __uint_as_float(u & 0xFFFF0000u); }

// ---------- session constraints (counter-evidenced) ----------
// R2/R3: grid-wide sync fusion DEAD (cg ~100us/sync; custom barrier worse).
// R4: pool at 64 blocks DEAD (1.9% occupancy, 62us).
// R5: SpMM-gather fused into GEMM DEAD (latency-bound, 67us vs ~25us split).
// R6: __threadfence() per pool block DEAD (~+20us: cross-XCD L2 writeback storm).
//     Atomic-only protocol needs NO fences: __syncthreads drains vmcnt (m97 asm),
//     pcnt add serializes at coherent point, reader uses agent-scope atomic loads.

// ---------- fused prep ----------
#define PREP_A (N_NODES * 32)            // x conv, 4 floats per item
#define PREP_B (TC * C1_DIM)             // W_cheb transpose (write-coalesced)
#define PREP_C (C1_DIM * C2_DIM)         // W_g1
#define PREP_D (C2_DIM * C3_DIM)         // W_g2
#define PREP_E N_NODES                   // gptr
#define PREP_F N_NODES                   // zero logits
#define PREP_H (N_GRAPHS * C3_DIM)       // zero pooled
#define PREP_G N_EDGES                   // degree count (guarded tail)
#define PREP_TOTAL (PREP_A + PREP_B + PREP_C + PREP_D + PREP_E + PREP_F + PREP_H + PREP_G)
__global__ void prep_kernel(const float* __restrict__ x, unsigned short* __restrict__ tcat,
                            const float* __restrict__ Wcheb, unsigned short* __restrict__ Wcb_t,
                            const float* __restrict__ Wg1, unsigned short* __restrict__ Wg1_t,
                            const float* __restrict__ Wg2, unsigned short* __restrict__ Wg2_t,
                            const int* __restrict__ batch, int* __restrict__ gptr,
                            float* __restrict__ logits, float* __restrict__ pooled,
                            const int* __restrict__ src, const int* __restrict__ dst,
                            int* __restrict__ cnt_s, int* __restrict__ cnt_d) {
    int id = blockIdx.x * blockDim.x + threadIdx.x;
    if (id < PREP_A) {
        int n = id >> 5, f = (id & 31) * 4;
        float4 v = *(const float4*)(x + (size_t)n * F_IN + f);
        ushort4 o; o.x = f2bf(v.x); o.y = f2bf(v.y); o.z = f2bf(v.z); o.w = f2bf(v.w);
        *(ushort4*)(tcat + (size_t)n * TC + f) = o;
        return;
    }
    id -= PREP_A;
    if (id < PREP_B) {
        int k = id % TC, n = id / TC;
        Wcb_t[(size_t)n * TC + k] = f2bf(Wcheb[(size_t)k * C1_DIM + n]);
        return;
    }
    id -= PREP_B;
    if (id < PREP_C) {
        int k = id % C1_DIM, n = id / C1_DIM;
        Wg1_t[(size_t)n * C1_DIM + k] = f2bf(Wg1[(size_t)k * C2_DIM + n]);
        return;
    }
    id -= PREP_C;
    if (id < PREP_D) {
        int k = id % C2_DIM, n = id / C2_DIM;
        Wg2_t[(size_t)n * C2_DIM + k] = f2bf(Wg2[(size_t)k * C3_DIM + n]);
        return;
    }
    id -= PREP_D;
    if (id < PREP_E) {
        int i = id;
        int b = batch[i];
        if (i == 0) { for (int g = 0; g <= b; g++) gptr[g] = 0; }
        else {
            int bp = batch[i - 1];
            for (int g = bp + 1; g <= b; g++) gptr[g] = i;
        }
        if (i == N_NODES - 1) { for (int g = b + 1; g <= N_GRAPHS; g++) gptr[g] = N_NODES; }
        return;
    }
    id -= PREP_E;
    if (id < PREP_F) { logits[id] = 0.0f; return; }
    id -= PREP_F;
    if (id < PREP_H) { pooled[id] = 0.0f; return; }
    id -= PREP_H;
    if (id < PREP_G) {   // guarded tail
        atomicAdd(&cnt_s[src[id]], 1);
        atomicAdd(&cnt_d[dst[id]], 1);
    }
}

// ---------- CSR fill with EMBEDDED per-block redundant scan (no scan stage) ----------
__global__ __launch_bounds__(256) void fill_scan_kernel(
        const int* __restrict__ src, const int* __restrict__ dst,
        const int* __restrict__ cnt_s, const int* __restrict__ cnt_d,
        int* __restrict__ rowptr, int* __restrict__ fillc,
        int2* __restrict__ ecb, int2* __restrict__ egc, int E, int n) {
    __shared__ int ldsc[N_NODES];
    __shared__ int sums[256];
    int tid = threadIdx.x;
    for (int i = tid; i < n; i += 256) ldsc[i] = cnt_d[i];
    __syncthreads();
    int chunk = (n + 255) / 256;
    int s0 = min(n, tid * chunk), s1 = min(n, s0 + chunk);
    int loc = 0;
    for (int i = s0; i < s1; i++) loc += ldsc[i];
    sums[tid] = loc;
    __syncthreads();
    for (int off = 1; off < 256; off <<= 1) {
        int t = (tid >= off) ? sums[tid - off] : 0;
        __syncthreads();
        sums[tid] += t;
        __syncthreads();
    }
    int pre = sums[tid] - loc;
    for (int i = s0; i < s1; i++) { int v = ldsc[i]; ldsc[i] = pre; pre += v; }
    __syncthreads();
    if (blockIdx.x == 0) {   // block 0 publishes rowptr for the gather kernels
        for (int i = tid; i < n; i += 256) rowptr[i] = ldsc[i];
        if (tid == 255) rowptr[n] = pre;
    }
    int e = blockIdx.x * 256 + tid;
    if (e >= E) return;
    int s = src[e], d = dst[e];
    int pos = ldsc[d] + atomicAdd(&fillc[d], 1);
    int cs = cnt_s[s], cd = cnt_s[d];
    float ds = (cs > 0) ? rsqrtf((float)cs) : 0.0f;
    float dd = (cd > 0) ? rsqrtf((float)cd) : 0.0f;
    float nr = rsqrtf((float)cnt_d[s] + 1.0f) * rsqrtf((float)cnt_d[d] + 1.0f);
    ecb[pos] = make_int2(s, __float_as_int(-(ds * dd)));
    egc[pos] = make_int2(s, __float_as_int(nr));
}

// ---------- Cheb gather over tcat slices (scalar-uniform edge pipeline) ----------
__global__ __launch_bounds__(256) void gather_cheb_bf(
        const unsigned short* __restrict__ tb, const int* __restrict__ rowptr,
        const int2* __restrict__ edges,
        const unsigned short* __restrict__ base, float alpha, float beta,
        unsigned short* __restrict__ outc, int n) {
    int w = (blockIdx.x * blockDim.x + threadIdx.x) >> 6;
    int lane = threadIdx.x & 63;
    if (w >= n) return;
    w = __builtin_amdgcn_readfirstlane(w);
    int rs = __builtin_amdgcn_readfirstlane(rowptr[w]);
    int re = __builtin_amdgcn_readfirstlane(rowptr[w + 1]);
    float a0 = 0.0f, a1 = 0.0f;
    for (int b = rs; b < re; b += 64) {
        int nv = min(64, re - b);
        int cl = 0, wlb = 0;
        if (b + lane < re) { int2 e = edges[b + lane]; cl = e.x; wlb = e.y; }
        int nk = (nv + 15) & ~15;   // pad lanes hold cl=0, w=0 (row 0 * 0 -> safe)
        for (int j = 0; j < nk; j += 16) {
            int ss[16]; float ww[16]; unsigned uu[16];
            #pragma unroll
            for (int q = 0; q < 16; q++) {
                ss[q] = __builtin_amdgcn_readlane(cl, j + q);
                ww[q] = __uint_as_float((unsigned)__builtin_amdgcn_readlane(wlb, j + q));
            }
            #pragma unroll
            for (int q = 0; q < 16; q++)
                uu[q] = *(const unsigned*)(tb + (size_t)ss[q] * TC + lane * 2);
            #pragma unroll
            for (int q = 0; q < 16; q++) { a0 += ww[q] * bf_lo(uu[q]); a1 += ww[q] * bf_hi(uu[q]); }
        }
    }
    if (base) {
        unsigned ub = ((const unsigned*)(base + (size_t)w * TC))[lane];
        a0 = alpha * a0 + beta * bf_lo(ub);
        a1 = alpha * a1 + beta * bf_hi(ub);
    } else {
        a0 *= alpha; a1 *= alpha;
    }
    ushort2 o; o.x = f2bf(a0); o.y = f2bf(a1);
    *(ushort2*)(outc + (size_t)w * TC + lane * 2) = o;
}

// ---------- GCN pre-aggregation, scalar-uniform edge pipeline ----------
template<int FPL>   // C = FPL*64, FPL in {2,4}
__global__ __launch_bounds__(256) void gather_gcn_pre(
        const unsigned short* __restrict__ tb, const int* __restrict__ rowptr,
        const int2* __restrict__ edges,
        const int* __restrict__ cnt_d, unsigned short* __restrict__ z, int n) {
    const int C = FPL * 64;
    int w = (blockIdx.x * blockDim.x + threadIdx.x) >> 6;
    int lane = threadIdx.x & 63;
    if (w >= n) return;
    w = __builtin_amdgcn_readfirstlane(w);
    int rs = __builtin_amdgcn_readfirstlane(rowptr[w]);
    int re = __builtin_amdgcn_readfirstlane(rowptr[w + 1]);
    float acc[FPL];
    #pragma unroll
    for (int q = 0; q < FPL; q++) acc[q] = 0.0f;
    for (int b = rs; b < re; b += 64) {
        int nv = min(64, re - b);
        int cl = 0, wlb = 0;
        if (b + lane < re) { int2 e = edges[b + lane]; cl = e.x; wlb = e.y; }
        int nk = (nv + 15) & ~15;
        for (int j = 0; j < nk; j += 16) {
            int ss[16]; float ww[16];
            #pragma unroll
            for (int q = 0; q < 16; q++) {
                ss[q] = __builtin_amdgcn_readlane(cl, j + q);
                ww[q] = __uint_as_float((unsigned)__builtin_amdgcn_readlane(wlb, j + q));
            }
            if constexpr (FPL == 2) {
                unsigned uu[16];
                #pragma unroll
                for (int q = 0; q < 16; q++)
                    uu[q] = *(const unsigned*)(tb + (size_t)ss[q] * C + lane * 2);
                #pragma unroll
                for (int q = 0; q < 16; q++) { acc[0] += ww[q] * bf_lo(uu[q]); acc[1] += ww[q] * bf_hi(uu[q]); }
            } else {
                uint2 uu[16];
                #pragma unroll
                for (int q = 0; q < 16; q++)
                    uu[q] = *(const uint2*)(tb + (size_t)ss[q] * C + lane * 4);
                #pragma unroll
                for (int q = 0; q < 16; q++) {
                    acc[0] += ww[q] * bf_lo(uu[q].x); acc[1] += ww[q] * bf_hi(uu[q].x);
                    acc[2] += ww[q] * bf_lo(uu[q].y); acc[3] += ww[q] * bf_hi(uu[q].y);
                }
            }
        }
    }
    float sn = 1.0f / (float)(cnt_d[w] + 1);   // dinv^2 self-loop term
    if constexpr (FPL == 2) {
        unsigned u = ((const unsigned*)(tb + (size_t)w * C))[lane];
        acc[0] += sn * bf_lo(u); acc[1] += sn * bf_hi(u);
        ushort2 o; o.x = f2bf(acc[0]); o.y = f2bf(acc[1]);
        *(ushort2*)(z + (size_t)w * C + lane * 2) = o;
    } else {
        uint2 u = ((const uint2*)(tb + (size_t)w * C))[lane];
        acc[0] += sn * bf_lo(u.x); acc[1] += sn * bf_hi(u.x);
        acc[2] += sn * bf_lo(u.y); acc[3] += sn * bf_hi(u.y);
        ushort4 o; o.x = f2bf(acc[0]); o.y = f2bf(acc[1]);
        o.z = f2bf(acc[2]); o.w = f2bf(acc[3]);
        *(ushort4*)(z + (size_t)w * C + lane * 4) = o;
    }
}

// ---------- bf16 MFMA GEMM, compile-time K ----------
template<int JT, int KC>
__global__ __launch_bounds__(256) void gemm_bf16(
        const unsigned short* __restrict__ A, const unsigned short* __restrict__ Bt,
        const float* __restrict__ bias,
        unsigned short* __restrict__ Cb, const float* __restrict__ wg,
        float* __restrict__ logits, int M, int N) {
    int m0 = blockIdx.y * 64, n0 = blockIdx.x * (JT * 32);
    int wave = threadIdx.x >> 6, lane = threadIdx.x & 63;
    int wm = (wave & 1) * 32, wn = (wave >> 1) * (JT * 16);
    int l15 = lane & 15, quad = lane >> 4;

    v4f acc[2][JT];
    #pragma unroll
    for (int i = 0; i < 2; i++)
        #pragma unroll
        for (int j = 0; j < JT; j++) acc[i][j] = (v4f){0.f, 0.f, 0.f, 0.f};

    const unsigned short* Ab[2]; bool av[2];
    #pragma unroll
    for (int i = 0; i < 2; i++) {
        int row = m0 + wm + i * 16 + l15;
        av[i] = row < M;
        Ab[i] = A + (size_t)(av[i] ? row : 0) * KC + quad * 8;
    }
    const unsigned short* Bb[JT];
    #pragma unroll
    for (int j = 0; j < JT; j++) {
        int coln = n0 + wn + j * 16 + l15;
        Bb[j] = Bt + (size_t)coln * KC + quad * 8;
    }
    const v8s zero8 = {0, 0, 0, 0, 0, 0, 0, 0};

    #pragma unroll
    for (int k0 = 0; k0 < KC; k0 += 32) {
        v8s a[2], b[JT];
        #pragma unroll
        for (int i = 0; i < 2; i++) a[i] = av[i] ? *(const v8s*)(Ab[i] + k0) : zero8;
        #pragma unroll
        for (int j = 0; j < JT; j++) b[j] = *(const v8s*)(Bb[j] + k0);
        #pragma unroll
        for (int i = 0; i < 2; i++)
            #pragma unroll
            for (int j = 0; j < JT; j++)
                acc[i][j] = __builtin_amdgcn_mfma_f32_16x16x32_bf16(a[i], b[j], acc[i][j], 0, 0, 0);
    }

    float bv[JT], wgj[JT];
    #pragma unroll
    for (int j = 0; j < JT; j++) {
        int coln = n0 + wn + j * 16 + l15;
        bv[j] = bias[coln];
        wgj[j] = wg ? wg[coln] : 0.0f;
    }
    #pragma unroll
    for (int i = 0; i < 2; i++) {
        #pragma unroll
        for (int r = 0; r < 4; r++) {
            int row = m0 + wm + i * 16 + quad * 4 + r;
            if (row >= M) continue;
            float gval = 0.0f;
            #pragma unroll
            for (int j = 0; j < JT; j++) {
                int coln = n0 + wn + j * 16 + l15;
                float v = fmaxf(acc[i][j][r] + bv[j], 0.0f);
                Cb[(size_t)row * N + coln] = f2bf(v);
                gval += v * wgj[j];
            }
            if (wg) {
                #pragma unroll
                for (int off = 1; off < 16; off <<= 1) gval += __shfl_xor(gval, off);
                if (l15 == 0) atomicAdd(&logits[row], gval);
            }
        }
    }
}

// ---------- pool (G x PSL blocks) + last-arriver FC, atomic-only protocol ----------
// R7: fences removed (atomic-only communication; __syncthreads drains vmcnt so
// pooled adds are performed before the pcnt arrival-add; reader uses agent-scope
// atomic loads at the coherent point). Tree reductions -> per-wave shfl (2 syncs
// instead of ~18). Grid.y 8 -> 16 for shorter serial weighted-sum slices.
__global__ __launch_bounds__(256) void pool_fc_kernel(
        const unsigned short* __restrict__ h3b,
        const float* __restrict__ logits, const int* __restrict__ gptr,
        float* __restrict__ pooled, int* __restrict__ pcnt,
        const float* __restrict__ Wfc, const float* __restrict__ bfc,
        float* __restrict__ out) {
    __shared__ float wred[8];
    __shared__ float pl[C3_DIM];
    __shared__ int lastf;
    int g = blockIdx.x, sl = blockIdx.y, tid = threadIdx.x;
    int lane = tid & 63, wv = tid >> 6;
    int gs = gptr[g], ge = gptr[g + 1];

    // max over graph logits (wave shfl + 4-value LDS exchange)
    float m = -INFINITY;
    for (int i = gs + tid; i < ge; i += 256) m = fmaxf(m, logits[i]);
    #pragma unroll
    for (int off = 32; off > 0; off >>= 1) m = fmaxf(m, __shfl_xor(m, off));
    if (lane == 0) wred[wv] = m;
    __syncthreads();
    m = fmaxf(fmaxf(wred[0], wred[1]), fmaxf(wred[2], wred[3]));

    // sum of exp
    float s = 0.0f;
    for (int i = gs + tid; i < ge; i += 256) s += expf(logits[i] - m);
    #pragma unroll
    for (int off = 32; off > 0; off >>= 1) s += __shfl_xor(s, off);
    if (lane == 0) wred[4 + wv] = s;
    __syncthreads();
    s = wred[4] + wred[5] + wred[6] + wred[7];
    float sinv = (s > 0.0f) ? 1.0f / s : 0.0f;

    // weighted pool over this block's slice
    int cnt = ge - gs;
    int i0 = gs + (cnt * sl) / PSL;
    int i1 = gs + (cnt * (sl + 1)) / PSL;
    float a0 = 0.0f, a1 = 0.0f;
    for (int i = i0; i < i1; i++) {
        float al = expf(logits[i] - m) * sinv;
        unsigned u = ((const unsigned*)(h3b + (size_t)i * C3_DIM))[tid];
        a0 += al * bf_lo(u);
        a1 += al * bf_hi(u);
    }
    if (i1 > i0) {
        atomicAdd(&pooled[(size_t)g * C3_DIM + tid * 2 + 0], a0);
        atomicAdd(&pooled[(size_t)g * C3_DIM + tid * 2 + 1], a1);
    }
    __syncthreads();                      // s_waitcnt vmcnt(0): pooled adds performed
    if (tid == 0) {
        int old = atomicAdd(&pcnt[g], 1); // coherent-point serialized after pooled adds
        lastf = (old == PSL - 1) ? 1 : 0;
    }
    __syncthreads();
    if (lastf) {                          // last block for g runs the FC
        pl[tid * 2 + 0] = __hip_atomic_load(&pooled[(size_t)g * C3_DIM + tid * 2 + 0],
                                            __ATOMIC_RELAXED, __HIP_MEMORY_SCOPE_AGENT);
        pl[tid * 2 + 1] = __hip_atomic_load(&pooled[(size_t)g * C3_DIM + tid * 2 + 1],
                                            __ATOMIC_RELAXED, __HIP_MEMORY_SCOPE_AGENT);
        __syncthreads();
        if (tid < 64) {
            float acc = -INFINITY;
            if (tid < NCLS) {
                acc = bfc[tid];
                for (int k = 0; k < C3_DIM; k++)
                    acc += pl[k] * Wfc[k * NCLS + tid];
            }
            float mm = acc;
            #pragma unroll
            for (int off = 8; off > 0; off >>= 1) mm = fmaxf(mm, __shfl_xor(mm, off, 16));
            float e = (tid < NCLS) ? expf(acc - mm) : 0.0f;
            float ss = e;
            #pragma unroll
            for (int off = 8; off > 0; off >>= 1) ss += __shfl_xor(ss, off, 16);
            if (tid < NCLS) out[g * NCLS + tid] = acc - mm - logf(ss);
        }
    }
}

// ---------- host ----------
extern "C" void kernel_launch(void* const* d_in, const int* in_sizes, int n_in,
                              void* d_out, int out_size, void* d_ws, size_t ws_size,
                              hipStream_t stream) {
    const float* x      = (const float*)d_in[0];
    const int*   ei     = (const int*)d_in[1];
    const int*   batch  = (const int*)d_in[2];
    const float* W_cheb = (const float*)d_in[3];
    const float* b_cheb = (const float*)d_in[4];
    const float* W_g1   = (const float*)d_in[5];
    const float* b_g1   = (const float*)d_in[6];
    const float* W_g2   = (const float*)d_in[7];
    const float* b_g2   = (const float*)d_in[8];
    const float* w_gate = (const float*)d_in[9];
    const float* W_fc   = (const float*)d_in[11];
    const float* b_fc   = (const float*)d_in[12];
    const int* src = ei;
    const int* dst = ei + N_EDGES;
    float* out = (float*)d_out;

    const int N = N_NODES, E = N_EDGES, G = N_GRAPHS;

    char* Wp = (char*)d_ws;
    auto alloc = [&](size_t bytes) {
        void* p = Wp;
        Wp += (bytes + 255) & ~(size_t)255;
        return p;
    };
    int*   cnt3    = (int*)alloc(((size_t)3 * N + G) * 4);  // cnt_s | cnt_d | fillc | pcnt
    int*   cnt_s   = cnt3;
    int*   cnt_d   = cnt3 + N;
    int*   fillc   = cnt3 + 2 * N;
    int*   pcnt    = cnt3 + 3 * N;
    int*   rowptr  = (int*)alloc((N + 1) * 4);
    int2*  ecb     = (int2*)alloc((size_t)E * 8);
    int2*  egc     = (int2*)alloc((size_t)E * 8);
    unsigned short* tcat  = (unsigned short*)alloc((size_t)N * TC * 2);
    unsigned short* h1b   = (unsigned short*)alloc((size_t)N * C1_DIM * 2);
    unsigned short* z1b   = (unsigned short*)alloc((size_t)N * C1_DIM * 2);
    unsigned short* h2b   = (unsigned short*)alloc((size_t)N * C2_DIM * 2);
    unsigned short* z2b   = (unsigned short*)alloc((size_t)N * C2_DIM * 2);
    unsigned short* h3b   = (unsigned short*)alloc((size_t)N * C3_DIM * 2);
    unsigned short* Wcb_t = (unsigned short*)alloc((size_t)TC * C1_DIM * 2);
    unsigned short* Wg1_t = (unsigned short*)alloc((size_t)C1_DIM * C2_DIM * 2);
    unsigned short* Wg2_t = (unsigned short*)alloc((size_t)C2_DIM * C3_DIM * 2);
    float* logits  = (float*)alloc(N * 4);
    int*   gptr    = (int*)alloc((G + 1) * 4);
    float* pooled  = (float*)alloc((size_t)G * C3_DIM * 4);

    dim3 blk(256);
    auto cdiv = [](int a, int b) { return (a + b - 1) / b; };

    // --- memset counters (+pcnt), fused prep ---
    hipMemsetAsync(cnt3, 0, ((size_t)3 * N + G) * sizeof(int), stream);
    hipLaunchKernelGGL(prep_kernel, dim3(cdiv(PREP_TOTAL, 256)), blk, 0, stream,
                       x, tcat, W_cheb, Wcb_t, W_g1, Wg1_t, W_g2, Wg2_t,
                       batch, gptr, logits, pooled, src, dst, cnt_s, cnt_d);

    // --- CSR fill with embedded redundant scan (scan stage eliminated) ---
    hipLaunchKernelGGL(fill_scan_kernel, dim3(cdiv(E, 256)), blk, 0, stream,
                       src, dst, cnt_s, cnt_d, rowptr, fillc, ecb, egc, E, N);

    const int NWB = cdiv(N, 4);   // gathers: 4 waves/block, 1 node/wave

    // --- Cheb recurrence on tcat slices ---
    hipLaunchKernelGGL(gather_cheb_bf, dim3(NWB), blk, 0, stream,
                       tcat + 0 * F_IN, rowptr, ecb,
                       (const unsigned short*)nullptr, 1.0f, 0.0f, tcat + 1 * F_IN, N);
    hipLaunchKernelGGL(gather_cheb_bf, dim3(NWB), blk, 0, stream,
                       tcat + 1 * F_IN, rowptr, ecb,
                       tcat + 0 * F_IN, 2.0f, -1.0f, tcat + 2 * F_IN, N);
    hipLaunchKernelGGL(gather_cheb_bf, dim3(NWB), blk, 0, stream,
                       tcat + 2 * F_IN, rowptr, ecb,
                       tcat + 1 * F_IN, 2.0f, -1.0f, tcat + 3 * F_IN, N);
    hipLaunchKernelGGL(gather_cheb_bf, dim3(NWB), blk, 0, stream,
                       tcat + 3 * F_IN, rowptr, ecb,
                       tcat + 2 * F_IN, 2.0f, -1.0f, tcat + 4 * F_IN, N);

    // --- GEMM1: h1 = relu(Tcat @ Wcb^T + b)  K=640 ---
    hipLaunchKernelGGL((gemm_bf16<2, TC>), dim3(C1_DIM / 64, cdiv(N, 64)), blk, 0, stream,
                       tcat, Wcb_t, b_cheb, h1b,
                       (const float*)nullptr, (float*)nullptr, N, C1_DIM);

    // --- GCN1 aggregate + GEMM2 (K=128) ---
    hipLaunchKernelGGL(gather_gcn_pre<2>, dim3(NWB), blk, 0, stream,
                       h1b, rowptr, egc, cnt_d, z1b, N);
    hipLaunchKernelGGL((gemm_bf16<4, C1_DIM>), dim3(C2_DIM / 128, cdiv(N, 64)), blk, 0, stream,
                       z1b, Wg1_t, b_g1, h2b,
                       (const float*)nullptr, (float*)nullptr, N, C2_DIM);

    // --- GCN2 aggregate + GEMM3 (K=256) + fused gate dot ---
    hipLaunchKernelGGL(gather_gcn_pre<4>, dim3(NWB), blk, 0, stream,
                       h2b, rowptr, egc, cnt_d, z2b, N);
    hipLaunchKernelGGL((gemm_bf16<4, C2_DIM>), dim3(C3_DIM / 128, cdiv(N, 64)), blk, 0, stream,
                       z2b, Wg2_t, b_g2, h3b,
                       w_gate, logits, N, C3_DIM);

    // --- pool (G x PSL, parallel) + last-arriver FC ---
    hipLaunchKernelGGL(pool_fc_kernel, dim3(G, PSL), blk, 0, stream,
                       h3b, logits, gptr, pooled, pcnt, W_fc, b_fc, out);
}

// Round 9
// 256.651 us; speedup vs baseline: 1.2458x; 1.0025x over previous
//
#include <hip/hip_runtime.h>
#include <hip/hip_bf16.h>
#include <math.h>

#define N_NODES 10000
#define N_EDGES 160000
#define N_GRAPHS 64
#define F_IN    128
#define C1_DIM  128
#define C2_DIM  256
#define C3_DIM  512
#define K_CHEB  5
#define NCLS    10
#define TC      (K_CHEB * F_IN)    // 640
#define PSL     16                 // pool slices per graph

typedef short v8s __attribute__((ext_vector_type(8)));
typedef float v4f __attribute__((ext_vector_type(4)));

// ---------- bf16 helpers ----------
static __device__ __forceinline__ unsigned short f2bf(float f) {
    unsigned u = __float_as_uint(f);
    unsigned r = (u + 0x7FFFu + ((u >> 16) & 1u)) >> 16;   // RNE
    return (unsigned short)r;
}
static __device__ __forceinline__ float bf_lo(unsigned u) { return __uint_as_float(u << 16); }
static __device__ __forceinline__ float bf_hi(unsigned u) { return __uint_as_float(u & 0xFFFF0000u); }

// ---------- session constraints (counter-evidenced) ----------
// R2/R3: grid-wide sync fusion DEAD (cg ~100us/sync; custom barrier worse).
// R4: pool at 64 blocks DEAD (1.9% occupancy, 62us).
// R5: SpMM-gather fused into GEMM DEAD (latency-bound, 67us vs ~25us split).
// R6: __threadfence() per pool block DEAD (cross-XCD L2 writeback storm).
// R7: atomic-only pool protocol + shfl reductions -> 257.3us session best.
// R8: infra failure (container), same source resubmitted.
// Dispatch graph is minimal: every adjacent pair has a cross-block dep
// (gathers read NEIGHBOR rows of the previous kernel's output).

// ---------- fused prep ----------
// R8: weight transposes vectorized 4-wide (ushort4 stores, /4 threads).
#define PREP_A (N_NODES * 32)            // x conv, 4 floats per item
#define PREP_B (TC * C1_DIM / 4)         // W_cheb transpose, 4 k-elems/thread
#define PREP_C (C1_DIM * C2_DIM / 4)     // W_g1
#define PREP_D (C2_DIM * C3_DIM / 4)     // W_g2
#define PREP_E N_NODES                   // gptr
#define PREP_F N_NODES                   // zero logits
#define PREP_H (N_GRAPHS * C3_DIM)       // zero pooled
#define PREP_G N_EDGES                   // degree count (guarded tail)
#define PREP_TOTAL (PREP_A + PREP_B + PREP_C + PREP_D + PREP_E + PREP_F + PREP_H + PREP_G)
__global__ void prep_kernel(const float* __restrict__ x, unsigned short* __restrict__ tcat,
                            const float* __restrict__ Wcheb, unsigned short* __restrict__ Wcb_t,
                            const float* __restrict__ Wg1, unsigned short* __restrict__ Wg1_t,
                            const float* __restrict__ Wg2, unsigned short* __restrict__ Wg2_t,
                            const int* __restrict__ batch, int* __restrict__ gptr,
                            float* __restrict__ logits, float* __restrict__ pooled,
                            const int* __restrict__ src, const int* __restrict__ dst,
                            int* __restrict__ cnt_s, int* __restrict__ cnt_d) {
    int id = blockIdx.x * blockDim.x + threadIdx.x;
    if (id < PREP_A) {
        int n = id >> 5, f = (id & 31) * 4;
        float4 v = *(const float4*)(x + (size_t)n * F_IN + f);
        ushort4 o; o.x = f2bf(v.x); o.y = f2bf(v.y); o.z = f2bf(v.z); o.w = f2bf(v.w);
        *(ushort4*)(tcat + (size_t)n * TC + f) = o;
        return;
    }
    id -= PREP_A;
    if (id < PREP_B) {
        int k = (id % (TC / 4)) * 4, n = id / (TC / 4);
        ushort4 o;
        o.x = f2bf(Wcheb[(size_t)(k + 0) * C1_DIM + n]);
        o.y = f2bf(Wcheb[(size_t)(k + 1) * C1_DIM + n]);
        o.z = f2bf(Wcheb[(size_t)(k + 2) * C1_DIM + n]);
        o.w = f2bf(Wcheb[(size_t)(k + 3) * C1_DIM + n]);
        *(ushort4*)(Wcb_t + (size_t)n * TC + k) = o;
        return;
    }
    id -= PREP_B;
    if (id < PREP_C) {
        int k = (id % (C1_DIM / 4)) * 4, n = id / (C1_DIM / 4);
        ushort4 o;
        o.x = f2bf(Wg1[(size_t)(k + 0) * C2_DIM + n]);
        o.y = f2bf(Wg1[(size_t)(k + 1) * C2_DIM + n]);
        o.z = f2bf(Wg1[(size_t)(k + 2) * C2_DIM + n]);
        o.w = f2bf(Wg1[(size_t)(k + 3) * C2_DIM + n]);
        *(ushort4*)(Wg1_t + (size_t)n * C1_DIM + k) = o;
        return;
    }
    id -= PREP_C;
    if (id < PREP_D) {
        int k = (id % (C2_DIM / 4)) * 4, n = id / (C2_DIM / 4);
        ushort4 o;
        o.x = f2bf(Wg2[(size_t)(k + 0) * C3_DIM + n]);
        o.y = f2bf(Wg2[(size_t)(k + 1) * C3_DIM + n]);
        o.z = f2bf(Wg2[(size_t)(k + 2) * C3_DIM + n]);
        o.w = f2bf(Wg2[(size_t)(k + 3) * C3_DIM + n]);
        *(ushort4*)(Wg2_t + (size_t)n * C2_DIM + k) = o;
        return;
    }
    id -= PREP_D;
    if (id < PREP_E) {
        int i = id;
        int b = batch[i];
        if (i == 0) { for (int g = 0; g <= b; g++) gptr[g] = 0; }
        else {
            int bp = batch[i - 1];
            for (int g = bp + 1; g <= b; g++) gptr[g] = i;
        }
        if (i == N_NODES - 1) { for (int g = b + 1; g <= N_GRAPHS; g++) gptr[g] = N_NODES; }
        return;
    }
    id -= PREP_E;
    if (id < PREP_F) { logits[id] = 0.0f; return; }
    id -= PREP_F;
    if (id < PREP_H) { pooled[id] = 0.0f; return; }
    id -= PREP_H;
    if (id < PREP_G) {   // guarded tail
        atomicAdd(&cnt_s[src[id]], 1);
        atomicAdd(&cnt_d[dst[id]], 1);
    }
}

// ---------- CSR fill with EMBEDDED per-block redundant scan (no scan stage) ----------
__global__ __launch_bounds__(256) void fill_scan_kernel(
        const int* __restrict__ src, const int* __restrict__ dst,
        const int* __restrict__ cnt_s, const int* __restrict__ cnt_d,
        int* __restrict__ rowptr, int* __restrict__ fillc,
        int2* __restrict__ ecb, int2* __restrict__ egc, int E, int n) {
    __shared__ int ldsc[N_NODES];
    __shared__ int sums[256];
    int tid = threadIdx.x;
    for (int i = tid; i < n; i += 256) ldsc[i] = cnt_d[i];
    __syncthreads();
    int chunk = (n + 255) / 256;
    int s0 = min(n, tid * chunk), s1 = min(n, s0 + chunk);
    int loc = 0;
    for (int i = s0; i < s1; i++) loc += ldsc[i];
    sums[tid] = loc;
    __syncthreads();
    for (int off = 1; off < 256; off <<= 1) {
        int t = (tid >= off) ? sums[tid - off] : 0;
        __syncthreads();
        sums[tid] += t;
        __syncthreads();
    }
    int pre = sums[tid] - loc;
    for (int i = s0; i < s1; i++) { int v = ldsc[i]; ldsc[i] = pre; pre += v; }
    __syncthreads();
    if (blockIdx.x == 0) {   // block 0 publishes rowptr for the gather kernels
        for (int i = tid; i < n; i += 256) rowptr[i] = ldsc[i];
        if (tid == 255) rowptr[n] = pre;
    }
    int e = blockIdx.x * 256 + tid;
    if (e >= E) return;
    int s = src[e], d = dst[e];
    int pos = ldsc[d] + atomicAdd(&fillc[d], 1);
    int cs = cnt_s[s], cd = cnt_s[d];
    float ds = (cs > 0) ? rsqrtf((float)cs) : 0.0f;
    float dd = (cd > 0) ? rsqrtf((float)cd) : 0.0f;
    float nr = rsqrtf((float)cnt_d[s] + 1.0f) * rsqrtf((float)cnt_d[d] + 1.0f);
    ecb[pos] = make_int2(s, __float_as_int(-(ds * dd)));
    egc[pos] = make_int2(s, __float_as_int(nr));
}

// ---------- Cheb gather over tcat slices (scalar-uniform edge pipeline) ----------
__global__ __launch_bounds__(256) void gather_cheb_bf(
        const unsigned short* __restrict__ tb, const int* __restrict__ rowptr,
        const int2* __restrict__ edges,
        const unsigned short* __restrict__ base, float alpha, float beta,
        unsigned short* __restrict__ outc, int n) {
    int w = (blockIdx.x * blockDim.x + threadIdx.x) >> 6;
    int lane = threadIdx.x & 63;
    if (w >= n) return;
    w = __builtin_amdgcn_readfirstlane(w);
    int rs = __builtin_amdgcn_readfirstlane(rowptr[w]);
    int re = __builtin_amdgcn_readfirstlane(rowptr[w + 1]);
    float a0 = 0.0f, a1 = 0.0f;
    for (int b = rs; b < re; b += 64) {
        int nv = min(64, re - b);
        int cl = 0, wlb = 0;
        if (b + lane < re) { int2 e = edges[b + lane]; cl = e.x; wlb = e.y; }
        int nk = (nv + 15) & ~15;   // pad lanes hold cl=0, w=0 (row 0 * 0 -> safe)
        for (int j = 0; j < nk; j += 16) {
            int ss[16]; float ww[16]; unsigned uu[16];
            #pragma unroll
            for (int q = 0; q < 16; q++) {
                ss[q] = __builtin_amdgcn_readlane(cl, j + q);
                ww[q] = __uint_as_float((unsigned)__builtin_amdgcn_readlane(wlb, j + q));
            }
            #pragma unroll
            for (int q = 0; q < 16; q++)
                uu[q] = *(const unsigned*)(tb + (size_t)ss[q] * TC + lane * 2);
            #pragma unroll
            for (int q = 0; q < 16; q++) { a0 += ww[q] * bf_lo(uu[q]); a1 += ww[q] * bf_hi(uu[q]); }
        }
    }
    if (base) {
        unsigned ub = ((const unsigned*)(base + (size_t)w * TC))[lane];
        a0 = alpha * a0 + beta * bf_lo(ub);
        a1 = alpha * a1 + beta * bf_hi(ub);
    } else {
        a0 *= alpha; a1 *= alpha;
    }
    ushort2 o; o.x = f2bf(a0); o.y = f2bf(a1);
    *(ushort2*)(outc + (size_t)w * TC + lane * 2) = o;
}

// ---------- GCN pre-aggregation, scalar-uniform edge pipeline ----------
template<int FPL>   // C = FPL*64, FPL in {2,4}
__global__ __launch_bounds__(256) void gather_gcn_pre(
        const unsigned short* __restrict__ tb, const int* __restrict__ rowptr,
        const int2* __restrict__ edges,
        const int* __restrict__ cnt_d, unsigned short* __restrict__ z, int n) {
    const int C = FPL * 64;
    int w = (blockIdx.x * blockDim.x + threadIdx.x) >> 6;
    int lane = threadIdx.x & 63;
    if (w >= n) return;
    w = __builtin_amdgcn_readfirstlane(w);
    int rs = __builtin_amdgcn_readfirstlane(rowptr[w]);
    int re = __builtin_amdgcn_readfirstlane(rowptr[w + 1]);
    float acc[FPL];
    #pragma unroll
    for (int q = 0; q < FPL; q++) acc[q] = 0.0f;
    for (int b = rs; b < re; b += 64) {
        int nv = min(64, re - b);
        int cl = 0, wlb = 0;
        if (b + lane < re) { int2 e = edges[b + lane]; cl = e.x; wlb = e.y; }
        int nk = (nv + 15) & ~15;
        for (int j = 0; j < nk; j += 16) {
            int ss[16]; float ww[16];
            #pragma unroll
            for (int q = 0; q < 16; q++) {
                ss[q] = __builtin_amdgcn_readlane(cl, j + q);
                ww[q] = __uint_as_float((unsigned)__builtin_amdgcn_readlane(wlb, j + q));
            }
            if constexpr (FPL == 2) {
                unsigned uu[16];
                #pragma unroll
                for (int q = 0; q < 16; q++)
                    uu[q] = *(const unsigned*)(tb + (size_t)ss[q] * C + lane * 2);
                #pragma unroll
                for (int q = 0; q < 16; q++) { acc[0] += ww[q] * bf_lo(uu[q]); acc[1] += ww[q] * bf_hi(uu[q]); }
            } else {
                uint2 uu[16];
                #pragma unroll
                for (int q = 0; q < 16; q++)
                    uu[q] = *(const uint2*)(tb + (size_t)ss[q] * C + lane * 4);
                #pragma unroll
                for (int q = 0; q < 16; q++) {
                    acc[0] += ww[q] * bf_lo(uu[q].x); acc[1] += ww[q] * bf_hi(uu[q].x);
                    acc[2] += ww[q] * bf_lo(uu[q].y); acc[3] += ww[q] * bf_hi(uu[q].y);
                }
            }
        }
    }
    float sn = 1.0f / (float)(cnt_d[w] + 1);   // dinv^2 self-loop term
    if constexpr (FPL == 2) {
        unsigned u = ((const unsigned*)(tb + (size_t)w * C))[lane];
        acc[0] += sn * bf_lo(u); acc[1] += sn * bf_hi(u);
        ushort2 o; o.x = f2bf(acc[0]); o.y = f2bf(acc[1]);
        *(ushort2*)(z + (size_t)w * C + lane * 2) = o;
    } else {
        uint2 u = ((const uint2*)(tb + (size_t)w * C))[lane];
        acc[0] += sn * bf_lo(u.x); acc[1] += sn * bf_hi(u.x);
        acc[2] += sn * bf_lo(u.y); acc[3] += sn * bf_hi(u.y);
        ushort4 o; o.x = f2bf(acc[0]); o.y = f2bf(acc[1]);
        o.z = f2bf(acc[2]); o.w = f2bf(acc[3]);
        *(ushort4*)(z + (size_t)w * C + lane * 4) = o;
    }
}

// ---------- bf16 MFMA GEMM, compile-time K ----------
template<int JT, int KC>
__global__ __launch_bounds__(256) void gemm_bf16(
        const unsigned short* __restrict__ A, const unsigned short* __restrict__ Bt,
        const float* __restrict__ bias,
        unsigned short* __restrict__ Cb, const float* __restrict__ wg,
        float* __restrict__ logits, int M, int N) {
    int m0 = blockIdx.y * 64, n0 = blockIdx.x * (JT * 32);
    int wave = threadIdx.x >> 6, lane = threadIdx.x & 63;
    int wm = (wave & 1) * 32, wn = (wave >> 1) * (JT * 16);
    int l15 = lane & 15, quad = lane >> 4;

    v4f acc[2][JT];
    #pragma unroll
    for (int i = 0; i < 2; i++)
        #pragma unroll
        for (int j = 0; j < JT; j++) acc[i][j] = (v4f){0.f, 0.f, 0.f, 0.f};

    const unsigned short* Ab[2]; bool av[2];
    #pragma unroll
    for (int i = 0; i < 2; i++) {
        int row = m0 + wm + i * 16 + l15;
        av[i] = row < M;
        Ab[i] = A + (size_t)(av[i] ? row : 0) * KC + quad * 8;
    }
    const unsigned short* Bb[JT];
    #pragma unroll
    for (int j = 0; j < JT; j++) {
        int coln = n0 + wn + j * 16 + l15;
        Bb[j] = Bt + (size_t)coln * KC + quad * 8;
    }
    const v8s zero8 = {0, 0, 0, 0, 0, 0, 0, 0};

    #pragma unroll
    for (int k0 = 0; k0 < KC; k0 += 32) {
        v8s a[2], b[JT];
        #pragma unroll
        for (int i = 0; i < 2; i++) a[i] = av[i] ? *(const v8s*)(Ab[i] + k0) : zero8;
        #pragma unroll
        for (int j = 0; j < JT; j++) b[j] = *(const v8s*)(Bb[j] + k0);
        #pragma unroll
        for (int i = 0; i < 2; i++)
            #pragma unroll
            for (int j = 0; j < JT; j++)
                acc[i][j] = __builtin_amdgcn_mfma_f32_16x16x32_bf16(a[i], b[j], acc[i][j], 0, 0, 0);
    }

    float bv[JT], wgj[JT];
    #pragma unroll
    for (int j = 0; j < JT; j++) {
        int coln = n0 + wn + j * 16 + l15;
        bv[j] = bias[coln];
        wgj[j] = wg ? wg[coln] : 0.0f;
    }
    #pragma unroll
    for (int i = 0; i < 2; i++) {
        #pragma unroll
        for (int r = 0; r < 4; r++) {
            int row = m0 + wm + i * 16 + quad * 4 + r;
            if (row >= M) continue;
            float gval = 0.0f;
            #pragma unroll
            for (int j = 0; j < JT; j++) {
                int coln = n0 + wn + j * 16 + l15;
                float v = fmaxf(acc[i][j][r] + bv[j], 0.0f);
                Cb[(size_t)row * N + coln] = f2bf(v);
                gval += v * wgj[j];
            }
            if (wg) {
                #pragma unroll
                for (int off = 1; off < 16; off <<= 1) gval += __shfl_xor(gval, off);
                if (l15 == 0) atomicAdd(&logits[row], gval);
            }
        }
    }
}

// ---------- pool (G x PSL blocks) + last-arriver FC, atomic-only protocol ----------
__global__ __launch_bounds__(256) void pool_fc_kernel(
        const unsigned short* __restrict__ h3b,
        const float* __restrict__ logits, const int* __restrict__ gptr,
        float* __restrict__ pooled, int* __restrict__ pcnt,
        const float* __restrict__ Wfc, const float* __restrict__ bfc,
        float* __restrict__ out) {
    __shared__ float wred[8];
    __shared__ float pl[C3_DIM];
    __shared__ int lastf;
    int g = blockIdx.x, sl = blockIdx.y, tid = threadIdx.x;
    int lane = tid & 63, wv = tid >> 6;
    int gs = gptr[g], ge = gptr[g + 1];

    // max over graph logits (wave shfl + 4-value LDS exchange)
    float m = -INFINITY;
    for (int i = gs + tid; i < ge; i += 256) m = fmaxf(m, logits[i]);
    #pragma unroll
    for (int off = 32; off > 0; off >>= 1) m = fmaxf(m, __shfl_xor(m, off));
    if (lane == 0) wred[wv] = m;
    __syncthreads();
    m = fmaxf(fmaxf(wred[0], wred[1]), fmaxf(wred[2], wred[3]));

    // sum of exp (fast exp: v_exp_f32 path)
    float s = 0.0f;
    for (int i = gs + tid; i < ge; i += 256) s += __expf(logits[i] - m);
    #pragma unroll
    for (int off = 32; off > 0; off >>= 1) s += __shfl_xor(s, off);
    if (lane == 0) wred[4 + wv] = s;
    __syncthreads();
    s = wred[4] + wred[5] + wred[6] + wred[7];
    float sinv = (s > 0.0f) ? 1.0f / s : 0.0f;

    // weighted pool over this block's slice
    int cnt = ge - gs;
    int i0 = gs + (cnt * sl) / PSL;
    int i1 = gs + (cnt * (sl + 1)) / PSL;
    float a0 = 0.0f, a1 = 0.0f;
    for (int i = i0; i < i1; i++) {
        float al = __expf(logits[i] - m) * sinv;
        unsigned u = ((const unsigned*)(h3b + (size_t)i * C3_DIM))[tid];
        a0 += al * bf_lo(u);
        a1 += al * bf_hi(u);
    }
    if (i1 > i0) {
        atomicAdd(&pooled[(size_t)g * C3_DIM + tid * 2 + 0], a0);
        atomicAdd(&pooled[(size_t)g * C3_DIM + tid * 2 + 1], a1);
    }
    __syncthreads();                      // s_waitcnt vmcnt(0): pooled adds performed
    if (tid == 0) {
        int old = atomicAdd(&pcnt[g], 1); // coherent-point serialized after pooled adds
        lastf = (old == PSL - 1) ? 1 : 0;
    }
    __syncthreads();
    if (lastf) {                          // last block for g runs the FC
        pl[tid * 2 + 0] = __hip_atomic_load(&pooled[(size_t)g * C3_DIM + tid * 2 + 0],
                                            __ATOMIC_RELAXED, __HIP_MEMORY_SCOPE_AGENT);
        pl[tid * 2 + 1] = __hip_atomic_load(&pooled[(size_t)g * C3_DIM + tid * 2 + 1],
                                            __ATOMIC_RELAXED, __HIP_MEMORY_SCOPE_AGENT);
        __syncthreads();
        if (tid < 64) {
            float acc = -INFINITY;
            if (tid < NCLS) {
                acc = bfc[tid];
                for (int k = 0; k < C3_DIM; k++)
                    acc += pl[k] * Wfc[k * NCLS + tid];
            }
            float mm = acc;
            #pragma unroll
            for (int off = 8; off > 0; off >>= 1) mm = fmaxf(mm, __shfl_xor(mm, off, 16));
            float e = (tid < NCLS) ? __expf(acc - mm) : 0.0f;
            float ss = e;
            #pragma unroll
            for (int off = 8; off > 0; off >>= 1) ss += __shfl_xor(ss, off, 16);
            if (tid < NCLS) out[g * NCLS + tid] = acc - mm - logf(ss);
        }
    }
}

// ---------- host ----------
extern "C" void kernel_launch(void* const* d_in, const int* in_sizes, int n_in,
                              void* d_out, int out_size, void* d_ws, size_t ws_size,
                              hipStream_t stream) {
    const float* x      = (const float*)d_in[0];
    const int*   ei     = (const int*)d_in[1];
    const int*   batch  = (const int*)d_in[2];
    const float* W_cheb = (const float*)d_in[3];
    const float* b_cheb = (const float*)d_in[4];
    const float* W_g1   = (const float*)d_in[5];
    const float* b_g1   = (const float*)d_in[6];
    const float* W_g2   = (const float*)d_in[7];
    const float* b_g2   = (const float*)d_in[8];
    const float* w_gate = (const float*)d_in[9];
    const float* W_fc   = (const float*)d_in[11];
    const float* b_fc   = (const float*)d_in[12];
    const int* src = ei;
    const int* dst = ei + N_EDGES;
    float* out = (float*)d_out;

    const int N = N_NODES, E = N_EDGES, G = N_GRAPHS;

    char* Wp = (char*)d_ws;
    auto alloc = [&](size_t bytes) {
        void* p = Wp;
        Wp += (bytes + 255) & ~(size_t)255;
        return p;
    };
    int*   cnt3    = (int*)alloc(((size_t)3 * N + G) * 4);  // cnt_s | cnt_d | fillc | pcnt
    int*   cnt_s   = cnt3;
    int*   cnt_d   = cnt3 + N;
    int*   fillc   = cnt3 + 2 * N;
    int*   pcnt    = cnt3 + 3 * N;
    int*   rowptr  = (int*)alloc((N + 1) * 4);
    int2*  ecb     = (int2*)alloc((size_t)E * 8);
    int2*  egc     = (int2*)alloc((size_t)E * 8);
    unsigned short* tcat  = (unsigned short*)alloc((size_t)N * TC * 2);
    unsigned short* h1b   = (unsigned short*)alloc((size_t)N * C1_DIM * 2);
    unsigned short* z1b   = (unsigned short*)alloc((size_t)N * C1_DIM * 2);
    unsigned short* h2b   = (unsigned short*)alloc((size_t)N * C2_DIM * 2);
    unsigned short* z2b   = (unsigned short*)alloc((size_t)N * C2_DIM * 2);
    unsigned short* h3b   = (unsigned short*)alloc((size_t)N * C3_DIM * 2);
    unsigned short* Wcb_t = (unsigned short*)alloc((size_t)TC * C1_DIM * 2);
    unsigned short* Wg1_t = (unsigned short*)alloc((size_t)C1_DIM * C2_DIM * 2);
    unsigned short* Wg2_t = (unsigned short*)alloc((size_t)C2_DIM * C3_DIM * 2);
    float* logits  = (float*)alloc(N * 4);
    int*   gptr    = (int*)alloc((G + 1) * 4);
    float* pooled  = (float*)alloc((size_t)G * C3_DIM * 4);

    dim3 blk(256);
    auto cdiv = [](int a, int b) { return (a + b - 1) / b; };

    // --- memset counters (+pcnt), fused prep ---
    hipMemsetAsync(cnt3, 0, ((size_t)3 * N + G) * sizeof(int), stream);
    hipLaunchKernelGGL(prep_kernel, dim3(cdiv(PREP_TOTAL, 256)), blk, 0, stream,
                       x, tcat, W_cheb, Wcb_t, W_g1, Wg1_t, W_g2, Wg2_t,
                       batch, gptr, logits, pooled, src, dst, cnt_s, cnt_d);

    // --- CSR fill with embedded redundant scan (scan stage eliminated) ---
    hipLaunchKernelGGL(fill_scan_kernel, dim3(cdiv(E, 256)), blk, 0, stream,
                       src, dst, cnt_s, cnt_d, rowptr, fillc, ecb, egc, E, N);

    const int NWB = cdiv(N, 4);   // gathers: 4 waves/block, 1 node/wave

    // --- Cheb recurrence on tcat slices ---
    hipLaunchKernelGGL(gather_cheb_bf, dim3(NWB), blk, 0, stream,
                       tcat + 0 * F_IN, rowptr, ecb,
                       (const unsigned short*)nullptr, 1.0f, 0.0f, tcat + 1 * F_IN, N);
    hipLaunchKernelGGL(gather_cheb_bf, dim3(NWB), blk, 0, stream,
                       tcat + 1 * F_IN, rowptr, ecb,
                       tcat + 0 * F_IN, 2.0f, -1.0f, tcat + 2 * F_IN, N);
    hipLaunchKernelGGL(gather_cheb_bf, dim3(NWB), blk, 0, stream,
                       tcat + 2 * F_IN, rowptr, ecb,
                       tcat + 1 * F_IN, 2.0f, -1.0f, tcat + 3 * F_IN, N);
    hipLaunchKernelGGL(gather_cheb_bf, dim3(NWB), blk, 0, stream,
                       tcat + 3 * F_IN, rowptr, ecb,
                       tcat + 2 * F_IN, 2.0f, -1.0f, tcat + 4 * F_IN, N);

    // --- GEMM1: h1 = relu(Tcat @ Wcb^T + b)  K=640 ---
    hipLaunchKernelGGL((gemm_bf16<2, TC>), dim3(C1_DIM / 64, cdiv(N, 64)), blk, 0, stream,
                       tcat, Wcb_t, b_cheb, h1b,
                       (const float*)nullptr, (float*)nullptr, N, C1_DIM);

    // --- GCN1 aggregate + GEMM2 (K=128) ---
    hipLaunchKernelGGL(gather_gcn_pre<2>, dim3(NWB), blk, 0, stream,
                       h1b, rowptr, egc, cnt_d, z1b, N);
    hipLaunchKernelGGL((gemm_bf16<4, C1_DIM>), dim3(C2_DIM / 128, cdiv(N, 64)), blk, 0, stream,
                       z1b, Wg1_t, b_g1, h2b,
                       (const float*)nullptr, (float*)nullptr, N, C2_DIM);

    // --- GCN2 aggregate + GEMM3 (K=256) + fused gate dot ---
    hipLaunchKernelGGL(gather_gcn_pre<4>, dim3(NWB), blk, 0, stream,
                       h2b, rowptr, egc, cnt_d, z2b, N);
    hipLaunchKernelGGL((gemm_bf16<4, C2_DIM>), dim3(C3_DIM / 128, cdiv(N, 64)), blk, 0, stream,
                       z2b, Wg2_t, b_g2, h3b,
                       w_gate, logits, N, C3_DIM);

    // --- pool (G x PSL, parallel) + last-arriver FC ---
    hipLaunchKernelGGL(pool_fc_kernel, dim3(G, PSL), blk, 0, stream,
                       h3b, logits, gptr, pooled, pcnt, W_fc, b_fc, out);
}